// Round 1
// baseline (11979.839 us; speedup 1.0000x reference)
//
#include <hip/hip_runtime.h>
#include <cstdint>
#include <cstddef>

#define D 128
#define H 8
#define NSRC 200000
#define NE0  100000
#define NE1  50000
#define E0N  1000000
#define E1N  500000

// ---------- helpers ----------
__device__ __forceinline__ unsigned flipf(float f) {
  unsigned u = __float_as_uint(f);
  return (u & 0x80000000u) ? ~u : (u | 0x80000000u);
}
__device__ __forceinline__ float unflipf(unsigned u) {
  return __uint_as_float((u & 0x80000000u) ? (u & 0x7fffffffu) : ~u);
}

// ---------- dense GEMM: out[N,128] = A[N,128] @ W[128,128], optional fused
// epilogue: out = 0.5*gemm + 0.5*accb/(s+1e-16)  (skip + normalized attention)
template <bool COMBINE>
__global__ __launch_bounds__(256) void gemm128(
    const float* __restrict__ A, const float* __restrict__ W,
    float* __restrict__ out, int N,
    const float* __restrict__ accb, const float* __restrict__ sb) {
  __shared__ float Ws[128 * 128];
  __shared__ float As[32 * 128];
  int tid = threadIdx.x;
  const float4* W4 = (const float4*)W;
  float4* Ws4 = (float4*)Ws;
#pragma unroll
  for (int i = 0; i < 16; ++i) Ws4[tid + 256 * i] = W4[tid + 256 * i];
  int row0 = blockIdx.x * 32;
  int rowsHere = N - row0;
  if (rowsHere > 32) rowsHere = 32;
  const float4* A4 = (const float4*)(A + (size_t)row0 * 128);
  float4* As4 = (float4*)As;
  for (int i = tid; i < rowsHere * 32; i += 256) As4[i] = A4[i];
  __syncthreads();

  int rg = tid >> 5;   // 0..7 -> rows rg*4 .. rg*4+3
  int cg = tid & 31;   // cols cg + 32*j
  float acc[4][4] = {};
  const float* ap0 = As + (rg * 4 + 0) * 128;
  const float* ap1 = As + (rg * 4 + 1) * 128;
  const float* ap2 = As + (rg * 4 + 2) * 128;
  const float* ap3 = As + (rg * 4 + 3) * 128;
  for (int k = 0; k < 128; k += 4) {
    float4 a0 = *(const float4*)(ap0 + k);
    float4 a1 = *(const float4*)(ap1 + k);
    float4 a2 = *(const float4*)(ap2 + k);
    float4 a3 = *(const float4*)(ap3 + k);
#pragma unroll
    for (int kk = 0; kk < 4; ++kk) {
      const float* wrow = Ws + (k + kk) * 128;
      float w0 = wrow[cg];
      float w1 = wrow[cg + 32];
      float w2 = wrow[cg + 64];
      float w3 = wrow[cg + 96];
      float a0k = (&a0.x)[kk], a1k = (&a1.x)[kk], a2k = (&a2.x)[kk], a3k = (&a3.x)[kk];
      acc[0][0] += a0k * w0; acc[0][1] += a0k * w1; acc[0][2] += a0k * w2; acc[0][3] += a0k * w3;
      acc[1][0] += a1k * w0; acc[1][1] += a1k * w1; acc[1][2] += a1k * w2; acc[1][3] += a1k * w3;
      acc[2][0] += a2k * w0; acc[2][1] += a2k * w1; acc[2][2] += a2k * w2; acc[2][3] += a2k * w3;
      acc[3][0] += a3k * w0; acc[3][1] += a3k * w1; acc[3][2] += a3k * w2; acc[3][3] += a3k * w3;
    }
  }
#pragma unroll
  for (int i = 0; i < 4; ++i) {
    int grow = row0 + rg * 4 + i;
    if (grow < N) {
#pragma unroll
      for (int j = 0; j < 4; ++j) {
        int c = cg + 32 * j;
        float val = acc[i][j];
        if (COMBINE) {
          float attn = accb[(size_t)grow * 128 + c] /
                       (sb[(size_t)grow * 8 + (c >> 4)] + 1e-16f);
          val = 0.5f * val + 0.5f * attn;
        }
        out[(size_t)grow * 128 + c] = val;
      }
    }
  }
}

// ---------- ke/ve precompute: ke = emb_type@We, ve = emb_attr@We  (4x128 each)
__global__ void prep_embs(const float* __restrict__ embA, const float* __restrict__ embB,
                          const float* __restrict__ We, float* __restrict__ keOut,
                          float* __restrict__ veOut) {
  int t = blockIdx.x * blockDim.x + threadIdx.x;
  if (t >= 512) return;
  int r = t >> 7, c = t & 127;
  float s0 = 0.f, s1 = 0.f;
  for (int k = 0; k < 128; ++k) {
    float w = We[k * 128 + c];
    s0 += embA[r * 128 + k] * w;
    s1 += embB[r * 128 + k] * w;
  }
  keOut[t] = s0;
  veOut[t] = s1;
}

// ---------- pass 1: logits + segment max (one thread per (edge, head))
__global__ __launch_bounds__(256) void edge_logits(
    const int* __restrict__ src, const int* __restrict__ dst, const int* __restrict__ et,
    const float* __restrict__ Q, const float* __restrict__ K, const float* __restrict__ ke,
    float* __restrict__ logits, unsigned* __restrict__ m, int E) {
  int t = blockIdx.x * 256 + threadIdx.x;
  if (t >= E * 8) return;
  int e = t >> 3, h = t & 7;
  int ss = src[e], dd = dst[e], ty = et[e];
  const float4* q4 = (const float4*)(Q + (size_t)dd * D + h * 16);
  const float4* k4 = (const float4*)(K + (size_t)ss * D + h * 16);
  const float4* t4 = (const float4*)(ke + ty * D + h * 16);
  float a = 0.f;
#pragma unroll
  for (int j = 0; j < 4; ++j) {
    float4 q = q4[j], kk = k4[j], kt = t4[j];
    a += q.x * (kk.x + kt.x) + q.y * (kk.y + kt.y) + q.z * (kk.z + kt.z) + q.w * (kk.w + kt.w);
  }
  float l = a * 0.25f;             // / sqrt(16)
  l = l >= 0.f ? l : 0.2f * l;     // leaky relu
  logits[t] = l;
  atomicMax(&m[(size_t)dd * 8 + h], flipf(l));
}

// ---------- pass 2: a=exp(l-m); s[dst,h]+=a; acc[dst,:] += a*v
__global__ __launch_bounds__(256) void edge_scatter(
    const int* __restrict__ src, const int* __restrict__ dst, const int* __restrict__ et,
    const float* __restrict__ V, const float* __restrict__ ve,
    const float* __restrict__ logits, const unsigned* __restrict__ m,
    float* __restrict__ sbuf, float* __restrict__ acc, int E) {
  int t = blockIdx.x * 256 + threadIdx.x;
  if (t >= E * 8) return;
  int e = t >> 3, h = t & 7;
  int ss = src[e], dd = dst[e], ty = et[e];
  float mm = unflipf(m[(size_t)dd * 8 + h]);
  float a = __expf(logits[t] - mm);
  atomicAdd(&sbuf[(size_t)dd * 8 + h], a);
  const float4* v4 = (const float4*)(V + (size_t)ss * D + h * 16);
  const float4* t4 = (const float4*)(ve + ty * D + h * 16);
  float* arow = acc + (size_t)dd * D + h * 16;
#pragma unroll
  for (int j = 0; j < 4; ++j) {
    float4 v = v4[j], vt = t4[j];
    atomicAdd(arow + 4 * j + 0, a * (v.x + vt.x));
    atomicAdd(arow + 4 * j + 1, a * (v.y + vt.y));
    atomicAdd(arow + 4 * j + 2, a * (v.z + vt.z));
    atomicAdd(arow + 4 * j + 3, a * (v.w + vt.w));
  }
}

// ---------- batch norm ----------
__global__ __launch_bounds__(256) void bn_reduce(const float* __restrict__ h,
                                                 float* __restrict__ sum,
                                                 float* __restrict__ sumsq, int N) {
  int c = threadIdx.x & 127;
  int rofs = threadIdx.x >> 7;  // 0..1
  float s0 = 0.f, s1 = 0.f;
  for (int r = blockIdx.x * 2 + rofs; r < N; r += gridDim.x * 2) {
    float v = h[(size_t)r * 128 + c];
    s0 += v;
    s1 += v * v;
  }
  __shared__ float ls[256], lq[256];
  ls[threadIdx.x] = s0;
  lq[threadIdx.x] = s1;
  __syncthreads();
  if (threadIdx.x < 128) {
    atomicAdd(&sum[c], ls[threadIdx.x] + ls[threadIdx.x + 128]);
    atomicAdd(&sumsq[c], lq[threadIdx.x] + lq[threadIdx.x + 128]);
  }
}

__global__ void bn_finalize(const float* __restrict__ sum, const float* __restrict__ sumsq,
                            const float* __restrict__ gamma, const float* __restrict__ beta,
                            float* __restrict__ scale, float* __restrict__ shift, float invN) {
  int c = threadIdx.x;
  if (c >= 128) return;
  float mu = sum[c] * invN;
  float var = sumsq[c] * invN - mu * mu;
  float inv = rsqrtf(var + 1e-5f);
  float sc = gamma[c] * inv;
  scale[c] = sc;
  shift[c] = beta[c] - mu * sc;
}

__global__ __launch_bounds__(256) void bn_apply(float* __restrict__ h,
                                                const float* __restrict__ scale,
                                                const float* __restrict__ shift, int total) {
  int i = blockIdx.x * 256 + threadIdx.x;
  if (i < total) {
    int c = i & 127;
    h[i] = h[i] * scale[c] + shift[c];
  }
}

// ---------- launch ----------
extern "C" void kernel_launch(void* const* d_in, const int* in_sizes, int n_in,
                              void* d_out, int out_size, void* d_ws, size_t ws_size,
                              hipStream_t stream) {
  const float* x        = (const float*)d_in[0];
  const int*   ei0      = (const int*)d_in[1];
  const int*   et0      = (const int*)d_in[2];
  const int*   ei1      = (const int*)d_in[3];
  const int*   et1      = (const int*)d_in[4];
  const float* emb_type = (const float*)d_in[5];
  const float* emb_attr = (const float*)d_in[6];
  const float* v2e_Wq   = (const float*)d_in[7];
  const float* v2e_Wk   = (const float*)d_in[8];
  const float* v2e_Wv   = (const float*)d_in[9];
  const float* v2e_We   = (const float*)d_in[10];
  const float* v2e_Wsk  = (const float*)d_in[11];
  const float* e2_Wq    = (const float*)d_in[12];
  const float* e2_Wk    = (const float*)d_in[13];
  const float* e2_Wv    = (const float*)d_in[14];
  const float* e2_We    = (const float*)d_in[15];
  const float* e2_Wsk   = (const float*)d_in[16];
  const float* bn_gamma = (const float*)d_in[17];
  const float* bn_beta  = (const float*)d_in[18];
  float* out = (float*)d_out;

  // workspace layout (floats)
  float* ws = (float*)d_ws;
  size_t off = 0;
  float* Kx = ws + off;      off += (size_t)NSRC * D;   // reused as K1 (NE0 rows)
  float* Vx = ws + off;      off += (size_t)NSRC * D;   // reused as V1
  float* Qb = ws + off;      off += (size_t)NE0 * D;    // reused as Q1
  float* logitsb = ws + off; off += (size_t)E0N * H;    // reused for E1
  unsigned* mb = (unsigned*)(ws + off); off += (size_t)NE0 * H;
  float* sb = ws + off;      off += (size_t)NE0 * H;
  float* hb = ws + off;      off += (size_t)NE0 * D;    // acc0 -> h (post BN)
  float* kep = ws + off;     off += 512;
  float* vep = ws + off;     off += 512;
  float* bnsum = ws + off;   off += 128;
  float* bnsq = ws + off;    off += 128;
  float* bnscale = ws + off; off += 128;
  float* bnshift = ws + off; off += 128;

  const int* src0 = ei0;
  const int* dst0 = ei0 + E0N;
  const int* src1 = ei1;
  const int* dst1 = ei1 + E1N;

  // ===== layer 0 =====
  hipMemsetAsync(hb, 0, (size_t)NE0 * D * 4, stream);
  hipMemsetAsync(mb, 0, (size_t)NE0 * H * 4, stream);
  hipMemsetAsync(sb, 0, (size_t)NE0 * H * 4, stream);
  hipMemsetAsync(bnsum, 0, 128 * 4, stream);
  hipMemsetAsync(bnsq, 0, 128 * 4, stream);

  prep_embs<<<2, 256, 0, stream>>>(emb_type, emb_attr, v2e_We, kep, vep);
  gemm128<false><<<(NSRC + 31) / 32, 256, 0, stream>>>(x, v2e_Wk, Kx, NSRC, nullptr, nullptr);
  gemm128<false><<<(NSRC + 31) / 32, 256, 0, stream>>>(x, v2e_Wv, Vx, NSRC, nullptr, nullptr);
  gemm128<false><<<(NE0 + 31) / 32, 256, 0, stream>>>(x, v2e_Wq, Qb, NE0, nullptr, nullptr);

  edge_logits<<<(E0N * 8 + 255) / 256, 256, 0, stream>>>(src0, dst0, et0, Qb, Kx, kep,
                                                         logitsb, mb, E0N);
  edge_scatter<<<(E0N * 8 + 255) / 256, 256, 0, stream>>>(src0, dst0, et0, Vx, vep,
                                                          logitsb, mb, sb, hb, E0N);
  // h_pre = 0.5*(x_dst@Wskip) + 0.5*acc/s   (in place into hb)
  gemm128<true><<<(NE0 + 31) / 32, 256, 0, stream>>>(x, v2e_Wsk, hb, NE0, hb, sb);

  bn_reduce<<<256, 256, 0, stream>>>(hb, bnsum, bnsq, NE0);
  bn_finalize<<<1, 128, 0, stream>>>(bnsum, bnsq, bn_gamma, bn_beta, bnscale, bnshift,
                                     1.0f / (float)NE0);
  bn_apply<<<(NE0 * D + 255) / 256, 256, 0, stream>>>(hb, bnscale, bnshift, NE0 * D);

  // ===== layer 1 =====
  hipMemsetAsync(out, 0, (size_t)NE1 * D * 4, stream);
  hipMemsetAsync(mb, 0, (size_t)NE1 * H * 4, stream);
  hipMemsetAsync(sb, 0, (size_t)NE1 * H * 4, stream);

  prep_embs<<<2, 256, 0, stream>>>(emb_type, emb_attr, e2_We, kep, vep);
  gemm128<false><<<(NE0 + 31) / 32, 256, 0, stream>>>(hb, e2_Wk, Kx, NE0, nullptr, nullptr);
  gemm128<false><<<(NE0 + 31) / 32, 256, 0, stream>>>(hb, e2_Wv, Vx, NE0, nullptr, nullptr);
  gemm128<false><<<(NE1 + 31) / 32, 256, 0, stream>>>(hb, e2_Wq, Qb, NE1, nullptr, nullptr);

  edge_logits<<<(E1N * 8 + 255) / 256, 256, 0, stream>>>(src1, dst1, et1, Qb, Kx, kep,
                                                         logitsb, mb, E1N);
  edge_scatter<<<(E1N * 8 + 255) / 256, 256, 0, stream>>>(src1, dst1, et1, Vx, vep,
                                                          logitsb, mb, sb, out, E1N);
  gemm128<true><<<(NE1 + 31) / 32, 256, 0, stream>>>(hb, e2_Wsk, out, NE1, out, sb);
}

// Round 2
// 1409.076 us; speedup vs baseline: 8.5019x; 8.5019x over previous
//
#include <hip/hip_runtime.h>
#include <cstdint>
#include <cstddef>

#define D 128
#define H 8
#define NSRC 200000
#define NE0  100000
#define NE1  50000
#define E0N  1000000
#define E1N  500000

// ---------- dense GEMM: out[N,128] = A[N,128] @ W[128,128], optional fused
// epilogue: out = 0.5*gemm + 0.5*attn   (skip + already-normalized attention)
// COMBINE may run in place (out == accb): each thread reads its own element
// before writing it.
template <bool COMBINE>
__global__ __launch_bounds__(256) void gemm128(
    const float* __restrict__ A, const float* __restrict__ W,
    float* __restrict__ out, int N, const float* __restrict__ accb) {
  __shared__ float Ws[128 * 128];
  __shared__ float As[32 * 128];
  int tid = threadIdx.x;
  const float4* W4 = (const float4*)W;
  float4* Ws4 = (float4*)Ws;
#pragma unroll
  for (int i = 0; i < 16; ++i) Ws4[tid + 256 * i] = W4[tid + 256 * i];
  int row0 = blockIdx.x * 32;
  int rowsHere = N - row0;
  if (rowsHere > 32) rowsHere = 32;
  const float4* A4 = (const float4*)(A + (size_t)row0 * 128);
  float4* As4 = (float4*)As;
  for (int i = tid; i < rowsHere * 32; i += 256) As4[i] = A4[i];
  __syncthreads();

  int rg = tid >> 5;   // 0..7 -> rows rg*4 .. rg*4+3
  int cg = tid & 31;   // cols cg + 32*j
  float acc[4][4] = {};
  const float* ap0 = As + (rg * 4 + 0) * 128;
  const float* ap1 = As + (rg * 4 + 1) * 128;
  const float* ap2 = As + (rg * 4 + 2) * 128;
  const float* ap3 = As + (rg * 4 + 3) * 128;
  for (int k = 0; k < 128; k += 4) {
    float4 a0 = *(const float4*)(ap0 + k);
    float4 a1 = *(const float4*)(ap1 + k);
    float4 a2 = *(const float4*)(ap2 + k);
    float4 a3 = *(const float4*)(ap3 + k);
#pragma unroll
    for (int kk = 0; kk < 4; ++kk) {
      const float* wrow = Ws + (k + kk) * 128;
      float w0 = wrow[cg];
      float w1 = wrow[cg + 32];
      float w2 = wrow[cg + 64];
      float w3 = wrow[cg + 96];
      float a0k = (&a0.x)[kk], a1k = (&a1.x)[kk], a2k = (&a2.x)[kk], a3k = (&a3.x)[kk];
      acc[0][0] += a0k * w0; acc[0][1] += a0k * w1; acc[0][2] += a0k * w2; acc[0][3] += a0k * w3;
      acc[1][0] += a1k * w0; acc[1][1] += a1k * w1; acc[1][2] += a1k * w2; acc[1][3] += a1k * w3;
      acc[2][0] += a2k * w0; acc[2][1] += a2k * w1; acc[2][2] += a2k * w2; acc[2][3] += a2k * w3;
      acc[3][0] += a3k * w0; acc[3][1] += a3k * w1; acc[3][2] += a3k * w2; acc[3][3] += a3k * w3;
    }
  }
#pragma unroll
  for (int i = 0; i < 4; ++i) {
    int grow = row0 + rg * 4 + i;
    if (grow < N) {
#pragma unroll
      for (int j = 0; j < 4; ++j) {
        int c = cg + 32 * j;
        float val = acc[i][j];
        if (COMBINE) {
          val = 0.5f * val + 0.5f * accb[(size_t)grow * 128 + c];
        }
        out[(size_t)grow * 128 + c] = val;
      }
    }
  }
}

// ---------- ke/ve precompute: ke = emb_type@We, ve = emb_attr@We  (4x128 each)
__global__ void prep_embs(const float* __restrict__ embA, const float* __restrict__ embB,
                          const float* __restrict__ We, float* __restrict__ keOut,
                          float* __restrict__ veOut) {
  int t = blockIdx.x * blockDim.x + threadIdx.x;
  if (t >= 512) return;
  int r = t >> 7, c = t & 127;
  float s0 = 0.f, s1 = 0.f;
  for (int k = 0; k < 128; ++k) {
    float w = We[k * 128 + c];
    s0 += embA[r * 128 + k] * w;
    s1 += embB[r * 128 + k] * w;
  }
  keOut[t] = s0;
  veOut[t] = s1;
}

// ---------- CSR build ----------
__global__ __launch_bounds__(256) void csr_count(const int* __restrict__ dst,
                                                 int* __restrict__ cnt, int E) {
  int t = blockIdx.x * 256 + threadIdx.x;
  if (t < E) atomicAdd(&cnt[dst[t]], 1);
}

// per-block exclusive scan over 1024 items (256 threads x 4)
__global__ __launch_bounds__(256) void scan1(const int* __restrict__ cnt,
                                             int* __restrict__ excl,
                                             int* __restrict__ blocksums, int N) {
  __shared__ int sh[256];
  int tid = threadIdx.x;
  int base = blockIdx.x * 1024 + tid * 4;
  int v0 = (base + 0 < N) ? cnt[base + 0] : 0;
  int v1 = (base + 1 < N) ? cnt[base + 1] : 0;
  int v2 = (base + 2 < N) ? cnt[base + 2] : 0;
  int v3 = (base + 3 < N) ? cnt[base + 3] : 0;
  int tsum = v0 + v1 + v2 + v3;
  sh[tid] = tsum;
  __syncthreads();
  for (int off = 1; off < 256; off <<= 1) {
    int t2 = (tid >= off) ? sh[tid - off] : 0;
    __syncthreads();
    sh[tid] += t2;
    __syncthreads();
  }
  int incl = sh[tid];
  if (tid == 255) blocksums[blockIdx.x] = incl;
  int run = incl - tsum;  // exclusive of this thread's chunk
  if (base + 0 < N) excl[base + 0] = run; run += v0;
  if (base + 1 < N) excl[base + 1] = run; run += v1;
  if (base + 2 < N) excl[base + 2] = run; run += v2;
  if (base + 3 < N) excl[base + 3] = run;
}

// single-block exclusive scan of block sums (nb <= 256)
__global__ void scan2(int* __restrict__ blocksums, int nb) {
  __shared__ int sh[256];
  int tid = threadIdx.x;
  int v = (tid < nb) ? blocksums[tid] : 0;
  sh[tid] = v;
  __syncthreads();
  for (int off = 1; off < 256; off <<= 1) {
    int t2 = (tid >= off) ? sh[tid - off] : 0;
    __syncthreads();
    sh[tid] += t2;
    __syncthreads();
  }
  if (tid < nb) blocksums[tid] = sh[tid] - v;
}

// add block offsets in place; copy to cursor; set offs[N]=E
__global__ __launch_bounds__(256) void scan3(int* __restrict__ offs,
                                             const int* __restrict__ blocksums,
                                             int* __restrict__ cursor, int N, int E) {
  int t = blockIdx.x * 256 + threadIdx.x;
  if (t < N) {
    int o = offs[t] + blocksums[t >> 10];
    offs[t] = o;
    cursor[t] = o;
  }
  if (t == 0) offs[N] = E;
}

__global__ __launch_bounds__(256) void csr_fill(const int* __restrict__ dst,
                                                int* __restrict__ cursor,
                                                int* __restrict__ elist, int E) {
  int t = blockIdx.x * 256 + threadIdx.x;
  if (t < E) {
    int p = atomicAdd(&cursor[dst[t]], 1);
    elist[p] = t;
  }
}

// ---------- flash-style per-destination attention (one wave per dst) ----------
// out = segment_softmax(leakyrelu(q.(k+ke)/4)) . (v+ve), normalized.
__global__ __launch_bounds__(256) void attn_per_dst(
    const int* __restrict__ src, const int* __restrict__ et,
    const int* __restrict__ offs, const int* __restrict__ elist,
    const float* __restrict__ Q, const float* __restrict__ K,
    const float* __restrict__ V, const float* __restrict__ ke,
    const float* __restrict__ ve, float* __restrict__ outAttn, int N) {
  int wave = (blockIdx.x * 256 + threadIdx.x) >> 6;
  int lane = threadIdx.x & 63;
  if (wave >= N) return;
  int d = wave;
  int dim = (lane >> 3) * 16 + (lane & 7) * 2;  // head*16 + l8*2
  float2 q = *(const float2*)(Q + (size_t)d * D + dim);
  q.x *= 0.25f;  // 1/sqrt(16) folded into q
  q.y *= 0.25f;
  float m = -INFINITY, s = 0.f;
  float accx = 0.f, accy = 0.f;
  int j0 = offs[d], j1 = offs[d + 1];
  for (int j = j0; j < j1; ++j) {
    int e = elist[j];
    int ss = src[e], ty = et[e];
    float2 kv = *(const float2*)(K + (size_t)ss * D + dim);
    float2 kt = *(const float2*)(ke + ty * D + dim);
    float2 vv = *(const float2*)(V + (size_t)ss * D + dim);
    float2 vt = *(const float2*)(ve + ty * D + dim);
    float p = q.x * (kv.x + kt.x) + q.y * (kv.y + kt.y);
    p += __shfl_xor(p, 1, 64);
    p += __shfl_xor(p, 2, 64);
    p += __shfl_xor(p, 4, 64);
    float l = p >= 0.f ? p : 0.2f * p;  // leaky relu
    float mn = fmaxf(m, l);
    float f = __expf(m - mn);   // 0 when m == -inf
    float a = __expf(l - mn);
    s = s * f + a;
    accx = accx * f + a * (vv.x + vt.x);
    accy = accy * f + a * (vv.y + vt.y);
    m = mn;
  }
  float inv = 1.f / (s + 1e-16f);
  float2 o;
  o.x = accx * inv;
  o.y = accy * inv;
  *(float2*)(outAttn + (size_t)d * D + dim) = o;
}

// ---------- batch norm ----------
__global__ __launch_bounds__(256) void bn_reduce(const float* __restrict__ h,
                                                 float* __restrict__ sum,
                                                 float* __restrict__ sumsq, int N) {
  int c = threadIdx.x & 127;
  int rofs = threadIdx.x >> 7;  // 0..1
  float s0 = 0.f, s1 = 0.f;
  for (int r = blockIdx.x * 2 + rofs; r < N; r += gridDim.x * 2) {
    float v = h[(size_t)r * 128 + c];
    s0 += v;
    s1 += v * v;
  }
  __shared__ float ls[256], lq[256];
  ls[threadIdx.x] = s0;
  lq[threadIdx.x] = s1;
  __syncthreads();
  if (threadIdx.x < 128) {
    atomicAdd(&sum[c], ls[threadIdx.x] + ls[threadIdx.x + 128]);
    atomicAdd(&sumsq[c], lq[threadIdx.x] + lq[threadIdx.x + 128]);
  }
}

__global__ void bn_finalize(const float* __restrict__ sum, const float* __restrict__ sumsq,
                            const float* __restrict__ gamma, const float* __restrict__ beta,
                            float* __restrict__ scale, float* __restrict__ shift, float invN) {
  int c = threadIdx.x;
  if (c >= 128) return;
  float mu = sum[c] * invN;
  float var = sumsq[c] * invN - mu * mu;
  float inv = rsqrtf(var + 1e-5f);
  float sc = gamma[c] * inv;
  scale[c] = sc;
  shift[c] = beta[c] - mu * sc;
}

__global__ __launch_bounds__(256) void bn_apply(float* __restrict__ h,
                                                const float* __restrict__ scale,
                                                const float* __restrict__ shift, int total) {
  int i = blockIdx.x * 256 + threadIdx.x;
  if (i < total) {
    int c = i & 127;
    h[i] = h[i] * scale[c] + shift[c];
  }
}

// ---------- launch ----------
extern "C" void kernel_launch(void* const* d_in, const int* in_sizes, int n_in,
                              void* d_out, int out_size, void* d_ws, size_t ws_size,
                              hipStream_t stream) {
  const float* x        = (const float*)d_in[0];
  const int*   ei0      = (const int*)d_in[1];
  const int*   et0      = (const int*)d_in[2];
  const int*   ei1      = (const int*)d_in[3];
  const int*   et1      = (const int*)d_in[4];
  const float* emb_type = (const float*)d_in[5];
  const float* emb_attr = (const float*)d_in[6];
  const float* v2e_Wq   = (const float*)d_in[7];
  const float* v2e_Wk   = (const float*)d_in[8];
  const float* v2e_Wv   = (const float*)d_in[9];
  const float* v2e_We   = (const float*)d_in[10];
  const float* v2e_Wsk  = (const float*)d_in[11];
  const float* e2_Wq    = (const float*)d_in[12];
  const float* e2_Wk    = (const float*)d_in[13];
  const float* e2_Wv    = (const float*)d_in[14];
  const float* e2_We    = (const float*)d_in[15];
  const float* e2_Wsk   = (const float*)d_in[16];
  const float* bn_gamma = (const float*)d_in[17];
  const float* bn_beta  = (const float*)d_in[18];
  float* out = (float*)d_out;

  // workspace layout (floats)
  float* ws = (float*)d_ws;
  size_t off = 0;
  float* Kx = ws + off;      off += (size_t)NSRC * D;   // layer1: K1 (NE0 rows) + attn1 in tail
  float* Vx = ws + off;      off += (size_t)NSRC * D;
  float* Qb = ws + off;      off += (size_t)NE0 * D;
  float* hb = ws + off;      off += (size_t)NE0 * D;    // attn0 -> h (in-place combine + BN)
  int* elist = (int*)(ws + off);   off += E0N;
  int* offs  = (int*)(ws + off);   off += NE0 + 1;
  int* cursor= (int*)(ws + off);   off += NE0;
  int* bsums = (int*)(ws + off);   off += 256;
  float* kep = ws + off;     off += 512;
  float* vep = ws + off;     off += 512;
  float* bnsum = ws + off;   off += 128;
  float* bnsq = ws + off;    off += 128;
  float* bnscale = ws + off; off += 128;
  float* bnshift = ws + off; off += 128;
  float* attn1 = Kx + (size_t)NE0 * D;  // tail of Kx (layer1 K uses only NE0 rows)

  const int* src0 = ei0;
  const int* dst0 = ei0 + E0N;
  const int* src1 = ei1;
  const int* dst1 = ei1 + E1N;

  // ===== layer 0 =====
  hipMemsetAsync(offs, 0, (size_t)(NE0 + 1) * 4, stream);  // scan1 input is cnt; reuse offs as cnt
  hipMemsetAsync(bnsum, 0, 128 * 4, stream);
  hipMemsetAsync(bnsq, 0, 128 * 4, stream);

  // CSR build (counts accumulated directly into offs, scanned in place)
  csr_count<<<(E0N + 255) / 256, 256, 0, stream>>>(dst0, offs, E0N);
  {
    int nb = (NE0 + 1023) / 1024;
    scan1<<<nb, 256, 0, stream>>>(offs, offs, bsums, NE0);
    scan2<<<1, 256, 0, stream>>>(bsums, nb);
    scan3<<<(NE0 + 255) / 256, 256, 0, stream>>>(offs, bsums, cursor, NE0, E0N);
  }
  csr_fill<<<(E0N + 255) / 256, 256, 0, stream>>>(dst0, cursor, elist, E0N);

  prep_embs<<<2, 256, 0, stream>>>(emb_type, emb_attr, v2e_We, kep, vep);
  gemm128<false><<<(NSRC + 31) / 32, 256, 0, stream>>>(x, v2e_Wk, Kx, NSRC, nullptr);
  gemm128<false><<<(NSRC + 31) / 32, 256, 0, stream>>>(x, v2e_Wv, Vx, NSRC, nullptr);
  gemm128<false><<<(NE0 + 31) / 32, 256, 0, stream>>>(x, v2e_Wq, Qb, NE0, nullptr);

  attn_per_dst<<<(NE0 + 3) / 4, 256, 0, stream>>>(src0, et0, offs, elist, Qb, Kx, Vx,
                                                  kep, vep, hb, NE0);
  // h = 0.5*(x_dst@Wskip) + 0.5*attn  (in place into hb)
  gemm128<true><<<(NE0 + 31) / 32, 256, 0, stream>>>(x, v2e_Wsk, hb, NE0, hb);

  bn_reduce<<<256, 256, 0, stream>>>(hb, bnsum, bnsq, NE0);
  bn_finalize<<<1, 128, 0, stream>>>(bnsum, bnsq, bn_gamma, bn_beta, bnscale, bnshift,
                                     1.0f / (float)NE0);
  bn_apply<<<(NE0 * D + 255) / 256, 256, 0, stream>>>(hb, bnscale, bnshift, NE0 * D);

  // ===== layer 1 =====
  hipMemsetAsync(offs, 0, (size_t)(NE1 + 1) * 4, stream);

  csr_count<<<(E1N + 255) / 256, 256, 0, stream>>>(dst1, offs, E1N);
  {
    int nb = (NE1 + 1023) / 1024;
    scan1<<<nb, 256, 0, stream>>>(offs, offs, bsums, NE1);
    scan2<<<1, 256, 0, stream>>>(bsums, nb);
    scan3<<<(NE1 + 255) / 256, 256, 0, stream>>>(offs, bsums, cursor, NE1, E1N);
  }
  csr_fill<<<(E1N + 255) / 256, 256, 0, stream>>>(dst1, cursor, elist, E1N);

  prep_embs<<<2, 256, 0, stream>>>(emb_type, emb_attr, e2_We, kep, vep);
  gemm128<false><<<(NE0 + 31) / 32, 256, 0, stream>>>(hb, e2_Wk, Kx, NE0, nullptr);
  gemm128<false><<<(NE0 + 31) / 32, 256, 0, stream>>>(hb, e2_Wv, Vx, NE0, nullptr);
  gemm128<false><<<(NE1 + 31) / 32, 256, 0, stream>>>(hb, e2_Wq, Qb, NE1, nullptr);

  attn_per_dst<<<(NE1 + 3) / 4, 256, 0, stream>>>(src1, et1, offs, elist, Qb, Kx, Vx,
                                                  kep, vep, attn1, NE1);
  gemm128<true><<<(NE1 + 31) / 32, 256, 0, stream>>>(hb, e2_Wsk, out, NE1, attn1);
}

// Round 3
// 1010.830 us; speedup vs baseline: 11.8515x; 1.3940x over previous
//
#include <hip/hip_runtime.h>
#include <cstdint>
#include <cstddef>

#define D 128
#define H 8
#define NSRC 200000
#define NE0  100000
#define NE1  50000
#define E0N  1000000
#define E1N  500000

typedef unsigned short u16;
typedef __attribute__((ext_vector_type(8))) short short8;
typedef __attribute__((ext_vector_type(4))) float f32x4;

#define LDSTRIDE 136  // bf16 elements per LDS row (272 B): 16B-aligned, 2-way banks only

// ---------- bf16 helpers ----------
__device__ __forceinline__ u16 f2bf(float f) {
  unsigned u = __float_as_uint(f);
  unsigned r = (u + 0x7fffu + ((u >> 16) & 1u)) >> 16;  // RNE
  return (u16)r;
}
__device__ __forceinline__ float bf2f(u16 u) {
  return __uint_as_float(((unsigned)u) << 16);
}

// ---------- weight transpose + cast: Wt[n][k] = bf16(W[k][n]), 8 matrices ----------
__global__ __launch_bounds__(256) void prep_weights(
    const float* w0, const float* w1, const float* w2, const float* w3,
    const float* w4, const float* w5, const float* w6, const float* w7,
    u16* __restrict__ wt) {
  const float* wsrc[8] = {w0, w1, w2, w3, w4, w5, w6, w7};
  int mat = blockIdx.x >> 3;
  int blk = blockIdx.x & 7;
  const float* W = wsrc[mat];
  u16* out = wt + mat * 16384;
  for (int i = blk * 2048 + threadIdx.x; i < (blk + 1) * 2048; i += 256) {
    int n = i >> 7, k = i & 127;
    out[i] = f2bf(W[k * 128 + n]);
  }
}

// ---------- MFMA GEMM: out[N,128] = A[N,128] @ W  (Wt pre-transposed bf16)
// MODE 0: store bf16.  MODE 1: out fp32 = 0.5*gemm + 0.5*accb (in-place safe).
template <int MODE>
__global__ __launch_bounds__(256) void gemm_mfma(
    const float* __restrict__ A, const u16* __restrict__ Wt,
    void* __restrict__ outP, int N, const float* __restrict__ accb) {
  __shared__ u16 As[128 * LDSTRIDE];
  __shared__ u16 Bs[128 * LDSTRIDE];
  int tid = threadIdx.x;
  int row0 = blockIdx.x * 128;
  int rowsHere = N - row0;
  if (rowsHere > 128) rowsHere = 128;
  // stage A: fp32 -> bf16, 4 elements/thread/iter
  for (int i = tid; i < 128 * 32; i += 256) {
    int r = i >> 5, c4 = (i & 31) * 4;
    ushort4 b4;
    if (r < rowsHere) {
      float4 a = *(const float4*)(A + (size_t)(row0 + r) * 128 + c4);
      b4.x = f2bf(a.x); b4.y = f2bf(a.y); b4.z = f2bf(a.z); b4.w = f2bf(a.w);
    } else {
      b4.x = b4.y = b4.z = b4.w = 0;
    }
    *(ushort4*)(As + r * LDSTRIDE + c4) = b4;
  }
  // stage Wt: contiguous bf16 16B chunks
  for (int i = tid; i < 128 * 16; i += 256) {
    int r = i >> 4, c8 = (i & 15) * 8;
    short8 w = *(const short8*)(Wt + r * 128 + c8);
    *(short8*)(Bs + r * LDSTRIDE + c8) = w;
  }
  __syncthreads();

  int w = tid >> 6, lane = tid & 63;
  int m0 = w * 32;
  int lrow = lane & 15, q = lane >> 4;
  f32x4 acc[2][8];
#pragma unroll
  for (int i = 0; i < 2; ++i)
#pragma unroll
    for (int j = 0; j < 8; ++j) acc[i][j] = (f32x4){0.f, 0.f, 0.f, 0.f};

  for (int kk = 0; kk < 128; kk += 32) {
    int ko = kk + q * 8;
    short8 a0 = *(const short8*)(As + (m0 + lrow) * LDSTRIDE + ko);
    short8 a1 = *(const short8*)(As + (m0 + 16 + lrow) * LDSTRIDE + ko);
#pragma unroll
    for (int j = 0; j < 8; ++j) {
      short8 b = *(const short8*)(Bs + (j * 16 + lrow) * LDSTRIDE + ko);
      acc[0][j] = __builtin_amdgcn_mfma_f32_16x16x32_bf16(a0, b, acc[0][j], 0, 0, 0);
      acc[1][j] = __builtin_amdgcn_mfma_f32_16x16x32_bf16(a1, b, acc[1][j], 0, 0, 0);
    }
  }
  // epilogue: C/D layout col=lane&15, row=q*4+reg
#pragma unroll
  for (int i = 0; i < 2; ++i) {
#pragma unroll
    for (int r = 0; r < 4; ++r) {
      int grow = row0 + m0 + i * 16 + q * 4 + r;
      if (grow < N) {
#pragma unroll
        for (int j = 0; j < 8; ++j) {
          int col = j * 16 + lrow;
          float v = acc[i][j][r];
          if (MODE == 0) {
            ((u16*)outP)[(size_t)grow * 128 + col] = f2bf(v);
          } else {
            float val = 0.5f * v + 0.5f * accb[(size_t)grow * 128 + col];
            ((float*)outP)[(size_t)grow * 128 + col] = val;
          }
        }
      }
    }
  }
}

// ---------- ke/ve precompute: ke = emb_type@We, ve = emb_attr@We  (4x128 each)
__global__ void prep_embs(const float* __restrict__ embA, const float* __restrict__ embB,
                          const float* __restrict__ We, float* __restrict__ keOut,
                          float* __restrict__ veOut) {
  int t = blockIdx.x * blockDim.x + threadIdx.x;
  if (t >= 512) return;
  int r = t >> 7, c = t & 127;
  float s0 = 0.f, s1 = 0.f;
  for (int k = 0; k < 128; ++k) {
    float w = We[k * 128 + c];
    s0 += embA[r * 128 + k] * w;
    s1 += embB[r * 128 + k] * w;
  }
  keOut[t] = s0;
  veOut[t] = s1;
}

// ---------- CSR build ----------
__global__ __launch_bounds__(256) void csr_count(const int* __restrict__ dst,
                                                 int* __restrict__ cnt, int E) {
  int t = blockIdx.x * 256 + threadIdx.x;
  if (t < E) atomicAdd(&cnt[dst[t]], 1);
}

__global__ __launch_bounds__(256) void scan1(const int* __restrict__ cnt,
                                             int* __restrict__ excl,
                                             int* __restrict__ blocksums, int N) {
  __shared__ int sh[256];
  int tid = threadIdx.x;
  int base = blockIdx.x * 1024 + tid * 4;
  int v0 = (base + 0 < N) ? cnt[base + 0] : 0;
  int v1 = (base + 1 < N) ? cnt[base + 1] : 0;
  int v2 = (base + 2 < N) ? cnt[base + 2] : 0;
  int v3 = (base + 3 < N) ? cnt[base + 3] : 0;
  int tsum = v0 + v1 + v2 + v3;
  sh[tid] = tsum;
  __syncthreads();
  for (int off = 1; off < 256; off <<= 1) {
    int t2 = (tid >= off) ? sh[tid - off] : 0;
    __syncthreads();
    sh[tid] += t2;
    __syncthreads();
  }
  int incl = sh[tid];
  if (tid == 255) blocksums[blockIdx.x] = incl;
  int run = incl - tsum;
  if (base + 0 < N) excl[base + 0] = run; run += v0;
  if (base + 1 < N) excl[base + 1] = run; run += v1;
  if (base + 2 < N) excl[base + 2] = run; run += v2;
  if (base + 3 < N) excl[base + 3] = run;
}

__global__ void scan2(int* __restrict__ blocksums, int nb) {
  __shared__ int sh[256];
  int tid = threadIdx.x;
  int v = (tid < nb) ? blocksums[tid] : 0;
  sh[tid] = v;
  __syncthreads();
  for (int off = 1; off < 256; off <<= 1) {
    int t2 = (tid >= off) ? sh[tid - off] : 0;
    __syncthreads();
    sh[tid] += t2;
    __syncthreads();
  }
  if (tid < nb) blocksums[tid] = sh[tid] - v;
}

__global__ __launch_bounds__(256) void scan3(int* __restrict__ offs,
                                             const int* __restrict__ blocksums,
                                             int* __restrict__ cursor, int N, int E) {
  int t = blockIdx.x * 256 + threadIdx.x;
  if (t < N) {
    int o = offs[t] + blocksums[t >> 10];
    offs[t] = o;
    cursor[t] = o;
  }
  if (t == 0) offs[N] = E;
}

__global__ __launch_bounds__(256) void csr_fill(const int* __restrict__ dst,
                                                int* __restrict__ cursor,
                                                int* __restrict__ elist, int E) {
  int t = blockIdx.x * 256 + threadIdx.x;
  if (t < E) {
    int p = atomicAdd(&cursor[dst[t]], 1);
    elist[p] = t;
  }
}

// ---------- flash-style per-destination attention (one wave per dst), bf16 QKV ----------
__global__ __launch_bounds__(256) void attn_per_dst(
    const int* __restrict__ src, const int* __restrict__ et,
    const int* __restrict__ offs, const int* __restrict__ elist,
    const u16* __restrict__ Q, const u16* __restrict__ K,
    const u16* __restrict__ V, const float* __restrict__ ke,
    const float* __restrict__ ve, float* __restrict__ outAttn, int N) {
  int wave = (blockIdx.x * 256 + threadIdx.x) >> 6;
  int lane = threadIdx.x & 63;
  if (wave >= N) return;
  int d = wave;
  int dim = (lane >> 3) * 16 + (lane & 7) * 2;  // head*16 + l8*2
  ushort2 qv = *(const ushort2*)(Q + (size_t)d * D + dim);
  float qx = bf2f(qv.x) * 0.25f;  // 1/sqrt(16) folded into q
  float qy = bf2f(qv.y) * 0.25f;
  float m = -INFINITY, s = 0.f;
  float accx = 0.f, accy = 0.f;
  int j0 = offs[d], j1 = offs[d + 1];
  for (int j = j0; j < j1; ++j) {
    int e = elist[j];
    int ss = src[e], ty = et[e];
    ushort2 kv = *(const ushort2*)(K + (size_t)ss * D + dim);
    ushort2 vv = *(const ushort2*)(V + (size_t)ss * D + dim);
    float2 kt = *(const float2*)(ke + ty * D + dim);
    float2 vt = *(const float2*)(ve + ty * D + dim);
    float p = qx * (bf2f(kv.x) + kt.x) + qy * (bf2f(kv.y) + kt.y);
    p += __shfl_xor(p, 1, 64);
    p += __shfl_xor(p, 2, 64);
    p += __shfl_xor(p, 4, 64);
    float l = p >= 0.f ? p : 0.2f * p;  // leaky relu
    float mn = fmaxf(m, l);
    float f = __expf(m - mn);
    float a = __expf(l - mn);
    s = s * f + a;
    accx = accx * f + a * (bf2f(vv.x) + vt.x);
    accy = accy * f + a * (bf2f(vv.y) + vt.y);
    m = mn;
  }
  float inv = 1.f / (s + 1e-16f);
  float2 o;
  o.x = accx * inv;
  o.y = accy * inv;
  *(float2*)(outAttn + (size_t)d * D + dim) = o;
}

// ---------- batch norm ----------
__global__ __launch_bounds__(256) void bn_reduce(const float* __restrict__ h,
                                                 float* __restrict__ sum,
                                                 float* __restrict__ sumsq, int N) {
  int c = threadIdx.x & 127;
  int rofs = threadIdx.x >> 7;
  float s0 = 0.f, s1 = 0.f;
  for (int r = blockIdx.x * 2 + rofs; r < N; r += gridDim.x * 2) {
    float v = h[(size_t)r * 128 + c];
    s0 += v;
    s1 += v * v;
  }
  __shared__ float ls[256], lq[256];
  ls[threadIdx.x] = s0;
  lq[threadIdx.x] = s1;
  __syncthreads();
  if (threadIdx.x < 128) {
    atomicAdd(&sum[c], ls[threadIdx.x] + ls[threadIdx.x + 128]);
    atomicAdd(&sumsq[c], lq[threadIdx.x] + lq[threadIdx.x + 128]);
  }
}

__global__ void bn_finalize(const float* __restrict__ sum, const float* __restrict__ sumsq,
                            const float* __restrict__ gamma, const float* __restrict__ beta,
                            float* __restrict__ scale, float* __restrict__ shift, float invN) {
  int c = threadIdx.x;
  if (c >= 128) return;
  float mu = sum[c] * invN;
  float var = sumsq[c] * invN - mu * mu;
  float inv = rsqrtf(var + 1e-5f);
  float sc = gamma[c] * inv;
  scale[c] = sc;
  shift[c] = beta[c] - mu * sc;
}

__global__ __launch_bounds__(256) void bn_apply(float* __restrict__ h,
                                                const float* __restrict__ scale,
                                                const float* __restrict__ shift, int total) {
  int i = blockIdx.x * 256 + threadIdx.x;
  if (i < total) {
    int c = i & 127;
    h[i] = h[i] * scale[c] + shift[c];
  }
}

// ---------- launch ----------
extern "C" void kernel_launch(void* const* d_in, const int* in_sizes, int n_in,
                              void* d_out, int out_size, void* d_ws, size_t ws_size,
                              hipStream_t stream) {
  const float* x        = (const float*)d_in[0];
  const int*   ei0      = (const int*)d_in[1];
  const int*   et0      = (const int*)d_in[2];
  const int*   ei1      = (const int*)d_in[3];
  const int*   et1      = (const int*)d_in[4];
  const float* emb_type = (const float*)d_in[5];
  const float* emb_attr = (const float*)d_in[6];
  const float* v2e_Wq   = (const float*)d_in[7];
  const float* v2e_Wk   = (const float*)d_in[8];
  const float* v2e_Wv   = (const float*)d_in[9];
  const float* v2e_We   = (const float*)d_in[10];
  const float* v2e_Wsk  = (const float*)d_in[11];
  const float* e2_Wq    = (const float*)d_in[12];
  const float* e2_Wk    = (const float*)d_in[13];
  const float* e2_Wv    = (const float*)d_in[14];
  const float* e2_We    = (const float*)d_in[15];
  const float* e2_Wsk   = (const float*)d_in[16];
  const float* bn_gamma = (const float*)d_in[17];
  const float* bn_beta  = (const float*)d_in[18];
  float* out = (float*)d_out;

  // workspace layout (bytes, 16B-aligned chunks)
  char* wsb = (char*)d_ws;
  size_t off = 0;
  u16* Kb = (u16*)(wsb + off);    off += (size_t)NSRC * D * 2;    // 51.2 MB (layer1 reuses)
  u16* Vb = (u16*)(wsb + off);    off += (size_t)NSRC * D * 2;
  u16* Qb = (u16*)(wsb + off);    off += (size_t)NE0 * D * 2;
  float* hb = (float*)(wsb + off);   off += (size_t)NE0 * D * 4;
  float* attn1 = (float*)(wsb + off); off += (size_t)NE1 * D * 4;
  u16* wtAll = (u16*)(wsb + off); off += 8 * 16384 * 2;
  int* elist = (int*)(wsb + off);  off += (size_t)E0N * 4;
  int* offs  = (int*)(wsb + off);  off += ((size_t)NE0 + 4) * 4;
  int* cursor= (int*)(wsb + off);  off += (size_t)NE0 * 4;
  int* bsums = (int*)(wsb + off);  off += 1024;
  float* kep = (float*)(wsb + off);  off += 512 * 4;
  float* vep = (float*)(wsb + off);  off += 512 * 4;
  float* bnsum = (float*)(wsb + off);  off += 512;
  float* bnsq = (float*)(wsb + off);   off += 512;
  float* bnscale = (float*)(wsb + off); off += 512;
  float* bnshift = (float*)(wsb + off); off += 512;

  u16* wtK0 = wtAll + 0 * 16384;
  u16* wtV0 = wtAll + 1 * 16384;
  u16* wtQ0 = wtAll + 2 * 16384;
  u16* wtS0 = wtAll + 3 * 16384;
  u16* wtK1 = wtAll + 4 * 16384;
  u16* wtV1 = wtAll + 5 * 16384;
  u16* wtQ1 = wtAll + 6 * 16384;
  u16* wtS1 = wtAll + 7 * 16384;

  const int* src0 = ei0;
  const int* dst0 = ei0 + E0N;
  const int* src1 = ei1;
  const int* dst1 = ei1 + E1N;

  prep_weights<<<64, 256, 0, stream>>>(v2e_Wk, v2e_Wv, v2e_Wq, v2e_Wsk,
                                       e2_Wk, e2_Wv, e2_Wq, e2_Wsk, wtAll);

  // ===== layer 0 =====
  hipMemsetAsync(offs, 0, (size_t)(NE0 + 1) * 4, stream);
  hipMemsetAsync(bnsum, 0, 128 * 4, stream);
  hipMemsetAsync(bnsq, 0, 128 * 4, stream);

  csr_count<<<(E0N + 255) / 256, 256, 0, stream>>>(dst0, offs, E0N);
  {
    int nb = (NE0 + 1023) / 1024;
    scan1<<<nb, 256, 0, stream>>>(offs, offs, bsums, NE0);
    scan2<<<1, 256, 0, stream>>>(bsums, nb);
    scan3<<<(NE0 + 255) / 256, 256, 0, stream>>>(offs, bsums, cursor, NE0, E0N);
  }
  csr_fill<<<(E0N + 255) / 256, 256, 0, stream>>>(dst0, cursor, elist, E0N);

  prep_embs<<<2, 256, 0, stream>>>(emb_type, emb_attr, v2e_We, kep, vep);
  gemm_mfma<0><<<(NSRC + 127) / 128, 256, 0, stream>>>(x, wtK0, Kb, NSRC, nullptr);
  gemm_mfma<0><<<(NSRC + 127) / 128, 256, 0, stream>>>(x, wtV0, Vb, NSRC, nullptr);
  gemm_mfma<0><<<(NE0 + 127) / 128, 256, 0, stream>>>(x, wtQ0, Qb, NE0, nullptr);

  attn_per_dst<<<(NE0 + 3) / 4, 256, 0, stream>>>(src0, et0, offs, elist, Qb, Kb, Vb,
                                                  kep, vep, hb, NE0);
  // h = 0.5*(x_dst@Wskip) + 0.5*attn  (in place into hb)
  gemm_mfma<1><<<(NE0 + 127) / 128, 256, 0, stream>>>(x, wtS0, hb, NE0, hb);

  bn_reduce<<<256, 256, 0, stream>>>(hb, bnsum, bnsq, NE0);
  bn_finalize<<<1, 128, 0, stream>>>(bnsum, bnsq, bn_gamma, bn_beta, bnscale, bnshift,
                                     1.0f / (float)NE0);
  bn_apply<<<(NE0 * D + 255) / 256, 256, 0, stream>>>(hb, bnscale, bnshift, NE0 * D);

  // ===== layer 1 =====
  hipMemsetAsync(offs, 0, (size_t)(NE1 + 1) * 4, stream);

  csr_count<<<(E1N + 255) / 256, 256, 0, stream>>>(dst1, offs, E1N);
  {
    int nb = (NE1 + 1023) / 1024;
    scan1<<<nb, 256, 0, stream>>>(offs, offs, bsums, NE1);
    scan2<<<1, 256, 0, stream>>>(bsums, nb);
    scan3<<<(NE1 + 255) / 256, 256, 0, stream>>>(offs, bsums, cursor, NE1, E1N);
  }
  csr_fill<<<(E1N + 255) / 256, 256, 0, stream>>>(dst1, cursor, elist, E1N);

  prep_embs<<<2, 256, 0, stream>>>(emb_type, emb_attr, e2_We, kep, vep);
  gemm_mfma<0><<<(NE0 + 127) / 128, 256, 0, stream>>>(hb, wtK1, Kb, NE0, nullptr);
  gemm_mfma<0><<<(NE0 + 127) / 128, 256, 0, stream>>>(hb, wtV1, Vb, NE0, nullptr);
  gemm_mfma<0><<<(NE1 + 127) / 128, 256, 0, stream>>>(hb, wtQ1, Qb, NE1, nullptr);

  attn_per_dst<<<(NE1 + 3) / 4, 256, 0, stream>>>(src1, et1, offs, elist, Qb, Kb, Vb,
                                                  kep, vep, attn1, NE1);
  gemm_mfma<1><<<(NE1 + 127) / 128, 256, 0, stream>>>(hb, wtS1, out, NE1, attn1);
}

// Round 4
// 852.531 us; speedup vs baseline: 14.0521x; 1.1857x over previous
//
#include <hip/hip_runtime.h>
#include <cstdint>
#include <cstddef>

#define D 128
#define H 8
#define NSRC 200000
#define NE0  100000
#define NE1  50000
#define E0N  1000000
#define E1N  500000

typedef unsigned short u16;
typedef __attribute__((ext_vector_type(8))) short short8;
typedef __attribute__((ext_vector_type(4))) float f32x4;

// ---------- bf16 helpers ----------
__device__ __forceinline__ u16 f2bf(float f) {
  unsigned u = __float_as_uint(f);
  unsigned r = (u + 0x7fffu + ((u >> 16) & 1u)) >> 16;  // RNE
  return (u16)r;
}
__device__ __forceinline__ float bf2f(u16 u) {
  return __uint_as_float(((unsigned)u) << 16);
}

// ---------- weight transpose + cast: Wt[n][k] = bf16(W[k][n]), 8 matrices ----------
__global__ __launch_bounds__(256) void prep_weights(
    const float* w0, const float* w1, const float* w2, const float* w3,
    const float* w4, const float* w5, const float* w6, const float* w7,
    u16* __restrict__ wt) {
  const float* wsrc[8] = {w0, w1, w2, w3, w4, w5, w6, w7};
  int mat = blockIdx.x >> 3;
  int blk = blockIdx.x & 7;
  const float* W = wsrc[mat];
  u16* out = wt + mat * 16384;
  for (int i = blk * 2048 + threadIdx.x; i < (blk + 1) * 2048; i += 256) {
    int n = i >> 7, k = i & 127;
    out[i] = f2bf(W[k * 128 + n]);
  }
}

// ---------- fp32 -> bf16 bulk cast ----------
__global__ __launch_bounds__(256) void cast_bf16(const float* __restrict__ x,
                                                 u16* __restrict__ xb, int total4) {
  int i = blockIdx.x * 256 + threadIdx.x;
  if (i < total4) {
    float4 a = ((const float4*)x)[i];
    ushort4 b;
    b.x = f2bf(a.x); b.y = f2bf(a.y); b.z = f2bf(a.z); b.w = f2bf(a.w);
    ((ushort4*)xb)[i] = b;
  }
}

// ---------- no-LDS dual-output MFMA GEMM ----------
// C0 = bf16(A @ W0), C1 = bf16(A @ W1).  A bf16 [N,128], Wt* bf16 [n][k].
// Block = 4 waves, each wave owns 32 rows; fragments loaded straight from
// global (A rows unique per wave; Wt is 32KB, L2-resident).
__global__ __launch_bounds__(256) void gemm_dual(
    const u16* __restrict__ A, const u16* __restrict__ Wt0,
    const u16* __restrict__ Wt1, u16* __restrict__ C0, u16* __restrict__ C1,
    int N) {
  int w = threadIdx.x >> 6, lane = threadIdx.x & 63;
  int lrow = lane & 15, q = lane >> 4;
  int row0 = blockIdx.x * 128 + w * 32;
  int ra = row0 + lrow;        // row group 0
  int rb = row0 + 16 + lrow;   // row group 1
  f32x4 acc[2][2][8];
#pragma unroll
  for (int o = 0; o < 2; ++o)
#pragma unroll
    for (int i = 0; i < 2; ++i)
#pragma unroll
      for (int j = 0; j < 8; ++j) acc[o][i][j] = (f32x4){0.f, 0.f, 0.f, 0.f};

  const short8 zero8 = {0, 0, 0, 0, 0, 0, 0, 0};
#pragma unroll
  for (int kk = 0; kk < 128; kk += 32) {
    int ko = kk + q * 8;
    short8 a0 = (ra < N) ? *(const short8*)(A + (size_t)ra * 128 + ko) : zero8;
    short8 a1 = (rb < N) ? *(const short8*)(A + (size_t)rb * 128 + ko) : zero8;
#pragma unroll
    for (int j = 0; j < 8; ++j) {
      short8 b0 = *(const short8*)(Wt0 + (j * 16 + lrow) * 128 + ko);
      short8 b1 = *(const short8*)(Wt1 + (j * 16 + lrow) * 128 + ko);
      acc[0][0][j] = __builtin_amdgcn_mfma_f32_16x16x32_bf16(a0, b0, acc[0][0][j], 0, 0, 0);
      acc[0][1][j] = __builtin_amdgcn_mfma_f32_16x16x32_bf16(a1, b0, acc[0][1][j], 0, 0, 0);
      acc[1][0][j] = __builtin_amdgcn_mfma_f32_16x16x32_bf16(a0, b1, acc[1][0][j], 0, 0, 0);
      acc[1][1][j] = __builtin_amdgcn_mfma_f32_16x16x32_bf16(a1, b1, acc[1][1][j], 0, 0, 0);
    }
  }
  // C/D layout: col = j*16 + (lane&15), row = q*4 + reg
#pragma unroll
  for (int o = 0; o < 2; ++o) {
    u16* C = o ? C1 : C0;
#pragma unroll
    for (int i = 0; i < 2; ++i) {
#pragma unroll
      for (int r = 0; r < 4; ++r) {
        int grow = row0 + i * 16 + q * 4 + r;
        if (grow < N) {
#pragma unroll
          for (int j = 0; j < 8; ++j) {
            C[(size_t)grow * 128 + j * 16 + lrow] = f2bf(acc[o][i][j][r]);
          }
        }
      }
    }
  }
}

// ---------- ke/ve precompute: ke = emb_type@We, ve = emb_attr@We  (4x128 each)
__global__ void prep_embs(const float* __restrict__ embA, const float* __restrict__ embB,
                          const float* __restrict__ We, float* __restrict__ keOut,
                          float* __restrict__ veOut) {
  int t = blockIdx.x * blockDim.x + threadIdx.x;
  if (t >= 512) return;
  int r = t >> 7, c = t & 127;
  float s0 = 0.f, s1 = 0.f;
  for (int k = 0; k < 128; ++k) {
    float w = We[k * 128 + c];
    s0 += embA[r * 128 + k] * w;
    s1 += embB[r * 128 + k] * w;
  }
  keOut[t] = s0;
  veOut[t] = s1;
}

// ---------- CSR build ----------
__global__ __launch_bounds__(256) void csr_count(const int* __restrict__ dst,
                                                 int* __restrict__ cnt, int E) {
  int t = blockIdx.x * 256 + threadIdx.x;
  if (t < E) atomicAdd(&cnt[dst[t]], 1);
}

__global__ __launch_bounds__(256) void scan1(const int* __restrict__ cnt,
                                             int* __restrict__ excl,
                                             int* __restrict__ blocksums, int N) {
  __shared__ int sh[256];
  int tid = threadIdx.x;
  int base = blockIdx.x * 1024 + tid * 4;
  int v0 = (base + 0 < N) ? cnt[base + 0] : 0;
  int v1 = (base + 1 < N) ? cnt[base + 1] : 0;
  int v2 = (base + 2 < N) ? cnt[base + 2] : 0;
  int v3 = (base + 3 < N) ? cnt[base + 3] : 0;
  int tsum = v0 + v1 + v2 + v3;
  sh[tid] = tsum;
  __syncthreads();
  for (int off = 1; off < 256; off <<= 1) {
    int t2 = (tid >= off) ? sh[tid - off] : 0;
    __syncthreads();
    sh[tid] += t2;
    __syncthreads();
  }
  int incl = sh[tid];
  if (tid == 255) blocksums[blockIdx.x] = incl;
  int run = incl - tsum;
  if (base + 0 < N) excl[base + 0] = run; run += v0;
  if (base + 1 < N) excl[base + 1] = run; run += v1;
  if (base + 2 < N) excl[base + 2] = run; run += v2;
  if (base + 3 < N) excl[base + 3] = run;
}

__global__ void scan2(int* __restrict__ blocksums, int nb) {
  __shared__ int sh[256];
  int tid = threadIdx.x;
  int v = (tid < nb) ? blocksums[tid] : 0;
  sh[tid] = v;
  __syncthreads();
  for (int off = 1; off < 256; off <<= 1) {
    int t2 = (tid >= off) ? sh[tid - off] : 0;
    __syncthreads();
    sh[tid] += t2;
    __syncthreads();
  }
  if (tid < nb) blocksums[tid] = sh[tid] - v;
}

__global__ __launch_bounds__(256) void scan3(int* __restrict__ offs,
                                             const int* __restrict__ blocksums,
                                             int* __restrict__ cursor, int N, int E) {
  int t = blockIdx.x * 256 + threadIdx.x;
  if (t < N) {
    int o = offs[t] + blocksums[t >> 10];
    offs[t] = o;
    cursor[t] = o;
  }
  if (t == 0) offs[N] = E;
}

// packs (src<<2)|ty into elist so attention needs no src/et gathers
__global__ __launch_bounds__(256) void csr_fill(const int* __restrict__ dst,
                                                const int* __restrict__ src,
                                                const int* __restrict__ et,
                                                int* __restrict__ cursor,
                                                int* __restrict__ elist, int E) {
  int t = blockIdx.x * 256 + threadIdx.x;
  if (t < E) {
    int p = atomicAdd(&cursor[dst[t]], 1);
    elist[p] = (src[t] << 2) | et[t];
  }
}

// ---------- fused flash attention + skip combine (one wave per dst) ----------
// out[d] = 0.5*skip[d] + 0.5 * softmax_e(leaky(q.(k+kt)/4)) . (v+vt)
__device__ __forceinline__ float sel4(float s0, float s1, float s2, float s3, int ty) {
  float a = (ty & 1) ? s1 : s0;
  float b = (ty & 1) ? s3 : s2;
  return (ty & 2) ? b : a;
}

__global__ __launch_bounds__(256) void attn_fused(
    const int* __restrict__ elist, const int* __restrict__ offs,
    const u16* __restrict__ Q, const u16* __restrict__ K,
    const u16* __restrict__ V, const float* __restrict__ ke,
    const float* __restrict__ ve, const u16* __restrict__ skipb,
    float* __restrict__ outp, int N) {
  int d = (blockIdx.x * 256 + threadIdx.x) >> 6;
  int lane = threadIdx.x & 63;
  if (d >= N) return;
  int dim = (lane >> 3) * 16 + (lane & 7) * 2;  // head*16 + l8*2
  ushort2 qv = *(const ushort2*)(Q + (size_t)d * D + dim);
  float qx = bf2f(qv.x) * 0.25f;  // 1/sqrt(16) folded in
  float qy = bf2f(qv.y) * 0.25f;

  // per-type constants hoisted out of the edge loop
  float2 kt0 = *(const float2*)(ke + 0 * D + dim);
  float2 kt1 = *(const float2*)(ke + 1 * D + dim);
  float2 kt2 = *(const float2*)(ke + 2 * D + dim);
  float2 kt3 = *(const float2*)(ke + 3 * D + dim);
  float2 vt0 = *(const float2*)(ve + 0 * D + dim);
  float2 vt1 = *(const float2*)(ve + 1 * D + dim);
  float2 vt2 = *(const float2*)(ve + 2 * D + dim);
  float2 vt3 = *(const float2*)(ve + 3 * D + dim);
  float qk0 = qx * kt0.x + qy * kt0.y;
  float qk1 = qx * kt1.x + qy * kt1.y;
  float qk2 = qx * kt2.x + qy * kt2.y;
  float qk3 = qx * kt3.x + qy * kt3.y;
#pragma unroll
  for (int mask = 1; mask <= 4; mask <<= 1) {
    qk0 += __shfl_xor(qk0, mask, 64);
    qk1 += __shfl_xor(qk1, mask, 64);
    qk2 += __shfl_xor(qk2, mask, 64);
    qk3 += __shfl_xor(qk3, mask, 64);
  }

  float m = -INFINITY, s = 0.f, accx = 0.f, accy = 0.f;
  int j0 = offs[d], j1 = offs[d + 1];
  for (int j = j0; j < j1; j += 4) {
    int n = j1 - j;
    int pk0 = elist[j];
    int pk1 = (n > 1) ? elist[j + 1] : pk0;
    int pk2 = (n > 2) ? elist[j + 2] : pk0;
    int pk3 = (n > 3) ? elist[j + 3] : pk0;
    int s0 = pk0 >> 2, t0 = pk0 & 3;
    int s1 = pk1 >> 2, t1 = pk1 & 3;
    int s2 = pk2 >> 2, t2 = pk2 & 3;
    int s3 = pk3 >> 2, t3 = pk3 & 3;
    // 8 concurrent gathers
    ushort2 k0 = *(const ushort2*)(K + (size_t)s0 * D + dim);
    ushort2 k1 = *(const ushort2*)(K + (size_t)s1 * D + dim);
    ushort2 k2 = *(const ushort2*)(K + (size_t)s2 * D + dim);
    ushort2 k3 = *(const ushort2*)(K + (size_t)s3 * D + dim);
    ushort2 w0 = *(const ushort2*)(V + (size_t)s0 * D + dim);
    ushort2 w1 = *(const ushort2*)(V + (size_t)s1 * D + dim);
    ushort2 w2 = *(const ushort2*)(V + (size_t)s2 * D + dim);
    ushort2 w3 = *(const ushort2*)(V + (size_t)s3 * D + dim);
    float p0 = qx * bf2f(k0.x) + qy * bf2f(k0.y);
    float p1 = qx * bf2f(k1.x) + qy * bf2f(k1.y);
    float p2 = qx * bf2f(k2.x) + qy * bf2f(k2.y);
    float p3 = qx * bf2f(k3.x) + qy * bf2f(k3.y);
#pragma unroll
    for (int mask = 1; mask <= 4; mask <<= 1) {
      p0 += __shfl_xor(p0, mask, 64);
      p1 += __shfl_xor(p1, mask, 64);
      p2 += __shfl_xor(p2, mask, 64);
      p3 += __shfl_xor(p3, mask, 64);
    }
    float l0 = p0 + sel4(qk0, qk1, qk2, qk3, t0);
    float l1 = p1 + sel4(qk0, qk1, qk2, qk3, t1);
    float l2 = p2 + sel4(qk0, qk1, qk2, qk3, t2);
    float l3 = p3 + sel4(qk0, qk1, qk2, qk3, t3);
    l0 = l0 >= 0.f ? l0 : 0.2f * l0;
    l1 = l1 >= 0.f ? l1 : 0.2f * l1;
    l2 = l2 >= 0.f ? l2 : 0.2f * l2;
    l3 = l3 >= 0.f ? l3 : 0.2f * l3;
    if (n < 2) l1 = -INFINITY;
    if (n < 3) l2 = -INFINITY;
    if (n < 4) l3 = -INFINITY;
    float mb = fmaxf(fmaxf(l0, l1), fmaxf(l2, l3));
    float mn = fmaxf(m, mb);
    float f = __expf(m - mn);  // 0 when m==-inf
    float a0 = __expf(l0 - mn);
    float a1 = __expf(l1 - mn);
    float a2 = __expf(l2 - mn);
    float a3 = __expf(l3 - mn);
    s = s * f + ((a0 + a1) + (a2 + a3));
    float vx0 = bf2f(w0.x) + sel4(vt0.x, vt1.x, vt2.x, vt3.x, t0);
    float vy0 = bf2f(w0.y) + sel4(vt0.y, vt1.y, vt2.y, vt3.y, t0);
    float vx1 = bf2f(w1.x) + sel4(vt0.x, vt1.x, vt2.x, vt3.x, t1);
    float vy1 = bf2f(w1.y) + sel4(vt0.y, vt1.y, vt2.y, vt3.y, t1);
    float vx2 = bf2f(w2.x) + sel4(vt0.x, vt1.x, vt2.x, vt3.x, t2);
    float vy2 = bf2f(w2.y) + sel4(vt0.y, vt1.y, vt2.y, vt3.y, t2);
    float vx3 = bf2f(w3.x) + sel4(vt0.x, vt1.x, vt2.x, vt3.x, t3);
    float vy3 = bf2f(w3.y) + sel4(vt0.y, vt1.y, vt2.y, vt3.y, t3);
    accx = accx * f + a0 * vx0 + a1 * vx1 + a2 * vx2 + a3 * vx3;
    accy = accy * f + a0 * vy0 + a1 * vy1 + a2 * vy2 + a3 * vy3;
    m = mn;
  }
  float inv = 1.f / (s + 1e-16f);
  ushort2 sk = *(const ushort2*)(skipb + (size_t)d * D + dim);
  float2 o;
  o.x = 0.5f * bf2f(sk.x) + 0.5f * accx * inv;
  o.y = 0.5f * bf2f(sk.y) + 0.5f * accy * inv;
  *(float2*)(outp + (size_t)d * D + dim) = o;
}

// ---------- batch norm ----------
__global__ __launch_bounds__(256) void bn_reduce(const float* __restrict__ h,
                                                 float* __restrict__ sum,
                                                 float* __restrict__ sumsq, int N) {
  int c = threadIdx.x & 127;
  int rofs = threadIdx.x >> 7;
  float s0 = 0.f, s1 = 0.f;
  for (int r = blockIdx.x * 2 + rofs; r < N; r += gridDim.x * 2) {
    float v = h[(size_t)r * 128 + c];
    s0 += v;
    s1 += v * v;
  }
  __shared__ float ls[256], lq[256];
  ls[threadIdx.x] = s0;
  lq[threadIdx.x] = s1;
  __syncthreads();
  if (threadIdx.x < 128) {
    atomicAdd(&sum[c], ls[threadIdx.x] + ls[threadIdx.x + 128]);
    atomicAdd(&sumsq[c], lq[threadIdx.x] + lq[threadIdx.x + 128]);
  }
}

__global__ void bn_finalize(const float* __restrict__ sum, const float* __restrict__ sumsq,
                            const float* __restrict__ gamma, const float* __restrict__ beta,
                            float* __restrict__ scale, float* __restrict__ shift, float invN) {
  int c = threadIdx.x;
  if (c >= 128) return;
  float mu = sum[c] * invN;
  float var = sumsq[c] * invN - mu * mu;
  float inv = rsqrtf(var + 1e-5f);
  float sc = gamma[c] * inv;
  scale[c] = sc;
  shift[c] = beta[c] - mu * sc;
}

// apply + cast to bf16 (layer-1 GEMM input)
__global__ __launch_bounds__(256) void bn_apply(const float* __restrict__ h,
                                                u16* __restrict__ hbf,
                                                const float* __restrict__ scale,
                                                const float* __restrict__ shift, int total) {
  int i = blockIdx.x * 256 + threadIdx.x;
  if (i < total) {
    int c = i & 127;
    hbf[i] = f2bf(h[i] * scale[c] + shift[c]);
  }
}

// ---------- launch ----------
extern "C" void kernel_launch(void* const* d_in, const int* in_sizes, int n_in,
                              void* d_out, int out_size, void* d_ws, size_t ws_size,
                              hipStream_t stream) {
  const float* x        = (const float*)d_in[0];
  const int*   ei0      = (const int*)d_in[1];
  const int*   et0      = (const int*)d_in[2];
  const int*   ei1      = (const int*)d_in[3];
  const int*   et1      = (const int*)d_in[4];
  const float* emb_type = (const float*)d_in[5];
  const float* emb_attr = (const float*)d_in[6];
  const float* v2e_Wq   = (const float*)d_in[7];
  const float* v2e_Wk   = (const float*)d_in[8];
  const float* v2e_Wv   = (const float*)d_in[9];
  const float* v2e_We   = (const float*)d_in[10];
  const float* v2e_Wsk  = (const float*)d_in[11];
  const float* e2_Wq    = (const float*)d_in[12];
  const float* e2_Wk    = (const float*)d_in[13];
  const float* e2_Wv    = (const float*)d_in[14];
  const float* e2_We    = (const float*)d_in[15];
  const float* e2_Wsk   = (const float*)d_in[16];
  const float* bn_gamma = (const float*)d_in[17];
  const float* bn_beta  = (const float*)d_in[18];
  float* out = (float*)d_out;

  // workspace layout (bytes; every chunk 16B-aligned)
  char* wsb = (char*)d_ws;
  size_t off = 0;
  u16* xb  = (u16*)(wsb + off);  off += (size_t)NSRC * D * 2;   // 51.2 MB
  u16* Kb  = (u16*)(wsb + off);  off += (size_t)NSRC * D * 2;
  u16* Vb  = (u16*)(wsb + off);  off += (size_t)NSRC * D * 2;
  u16* Qb  = (u16*)(wsb + off);  off += (size_t)NE0 * D * 2;
  u16* Sb  = (u16*)(wsb + off);  off += (size_t)NE0 * D * 2;    // raw skip (bf16)
  float* hb = (float*)(wsb + off); off += (size_t)NE0 * D * 4;  // layer-0 output fp32
  u16* hbf = (u16*)(wsb + off);  off += (size_t)NE0 * D * 2;    // post-BN bf16
  u16* wtAll = (u16*)(wsb + off); off += 8 * 16384 * 2;
  int* elist = (int*)(wsb + off);  off += (size_t)E0N * 4;
  int* offs  = (int*)(wsb + off);  off += ((size_t)NE0 + 8) * 4;
  int* cursor= (int*)(wsb + off);  off += (size_t)NE0 * 4;
  int* bsums = (int*)(wsb + off);  off += 1024;
  float* kep = (float*)(wsb + off);  off += 512 * 4;
  float* vep = (float*)(wsb + off);  off += 512 * 4;
  float* bnsum = (float*)(wsb + off);  off += 512;
  float* bnsq = (float*)(wsb + off);   off += 512;
  float* bnscale = (float*)(wsb + off); off += 512;
  float* bnshift = (float*)(wsb + off); off += 512;

  u16* wtK0 = wtAll + 0 * 16384;
  u16* wtV0 = wtAll + 1 * 16384;
  u16* wtQ0 = wtAll + 2 * 16384;
  u16* wtS0 = wtAll + 3 * 16384;
  u16* wtK1 = wtAll + 4 * 16384;
  u16* wtV1 = wtAll + 5 * 16384;
  u16* wtQ1 = wtAll + 6 * 16384;
  u16* wtS1 = wtAll + 7 * 16384;

  const int* src0 = ei0;
  const int* dst0 = ei0 + E0N;
  const int* src1 = ei1;
  const int* dst1 = ei1 + E1N;

  prep_weights<<<64, 256, 0, stream>>>(v2e_Wk, v2e_Wv, v2e_Wq, v2e_Wsk,
                                       e2_Wk, e2_Wv, e2_Wq, e2_Wsk, wtAll);
  cast_bf16<<<(NSRC * D / 4 + 255) / 256, 256, 0, stream>>>(x, xb, NSRC * D / 4);

  // ===== layer 0 =====
  hipMemsetAsync(offs, 0, (size_t)(NE0 + 1) * 4, stream);
  hipMemsetAsync(bnsum, 0, 128 * 4, stream);
  hipMemsetAsync(bnsq, 0, 128 * 4, stream);

  csr_count<<<(E0N + 255) / 256, 256, 0, stream>>>(dst0, offs, E0N);
  {
    int nb = (NE0 + 1023) / 1024;
    scan1<<<nb, 256, 0, stream>>>(offs, offs, bsums, NE0);
    scan2<<<1, 256, 0, stream>>>(bsums, nb);
    scan3<<<(NE0 + 255) / 256, 256, 0, stream>>>(offs, bsums, cursor, NE0, E0N);
  }
  csr_fill<<<(E0N + 255) / 256, 256, 0, stream>>>(dst0, src0, et0, cursor, elist, E0N);

  prep_embs<<<2, 256, 0, stream>>>(emb_type, emb_attr, v2e_We, kep, vep);
  gemm_dual<<<(NSRC + 127) / 128, 256, 0, stream>>>(xb, wtK0, wtV0, Kb, Vb, NSRC);
  gemm_dual<<<(NE0 + 127) / 128, 256, 0, stream>>>(xb, wtQ0, wtS0, Qb, Sb, NE0);

  attn_fused<<<(NE0 + 3) / 4, 256, 0, stream>>>(elist, offs, Qb, Kb, Vb, kep, vep,
                                                Sb, hb, NE0);

  bn_reduce<<<256, 256, 0, stream>>>(hb, bnsum, bnsq, NE0);
  bn_finalize<<<1, 128, 0, stream>>>(bnsum, bnsq, bn_gamma, bn_beta, bnscale, bnshift,
                                     1.0f / (float)NE0);
  bn_apply<<<(NE0 * D + 255) / 256, 256, 0, stream>>>(hb, hbf, bnscale, bnshift, NE0 * D);

  // ===== layer 1 =====
  hipMemsetAsync(offs, 0, (size_t)(NE1 + 1) * 4, stream);

  csr_count<<<(E1N + 255) / 256, 256, 0, stream>>>(dst1, offs, E1N);
  {
    int nb = (NE1 + 1023) / 1024;
    scan1<<<nb, 256, 0, stream>>>(offs, offs, bsums, NE1);
    scan2<<<1, 256, 0, stream>>>(bsums, nb);
    scan3<<<(NE1 + 255) / 256, 256, 0, stream>>>(offs, bsums, cursor, NE1, E1N);
  }
  csr_fill<<<(E1N + 255) / 256, 256, 0, stream>>>(dst1, src1, et1, cursor, elist, E1N);

  prep_embs<<<2, 256, 0, stream>>>(emb_type, emb_attr, e2_We, kep, vep);
  gemm_dual<<<(NE0 + 127) / 128, 256, 0, stream>>>(hbf, wtK1, wtV1, Kb, Vb, NE0);
  gemm_dual<<<(NE1 + 127) / 128, 256, 0, stream>>>(hbf, wtQ1, wtS1, Qb, Sb, NE1);

  attn_fused<<<(NE1 + 3) / 4, 256, 0, stream>>>(elist, offs, Qb, Kb, Vb, kep, vep,
                                                Sb, out, NE1);
}

// Round 5
// 749.163 us; speedup vs baseline: 15.9910x; 1.1380x over previous
//
#include <hip/hip_runtime.h>
#include <cstdint>
#include <cstddef>

#define D 128
#define H 8
#define NSRC 200000
#define NE0  100000
#define NE1  50000
#define E0N  1000000
#define E1N  500000
#define NT   (NE0 + NE1)       // concatenated dst bins
#define ET   (E0N + E1N)       // concatenated edges

typedef unsigned short u16;
typedef __attribute__((ext_vector_type(8))) short short8;
typedef __attribute__((ext_vector_type(4))) float f32x4;

// ---------- bf16 helpers ----------
__device__ __forceinline__ u16 f2bf(float f) {
  unsigned u = __float_as_uint(f);
  unsigned r = (u + 0x7fffu + ((u >> 16) & 1u)) >> 16;  // RNE
  return (u16)r;
}
__device__ __forceinline__ float bf2f(u16 u) {
  return __uint_as_float(((unsigned)u) << 16);
}

// ---------- weight transpose + cast: Wt[n][k] = bf16(W[k][n]), 8 matrices ----------
__global__ __launch_bounds__(256) void prep_weights(
    const float* w0, const float* w1, const float* w2, const float* w3,
    const float* w4, const float* w5, const float* w6, const float* w7,
    u16* __restrict__ wt) {
  const float* wsrc[8] = {w0, w1, w2, w3, w4, w5, w6, w7};
  int mat = blockIdx.x >> 3;
  int blk = blockIdx.x & 7;
  const float* W = wsrc[mat];
  u16* out = wt + mat * 16384;
  for (int i = blk * 2048 + threadIdx.x; i < (blk + 1) * 2048; i += 256) {
    int n = i >> 7, k = i & 127;
    out[i] = f2bf(W[k * 128 + n]);
  }
}

// ---------- fp32 -> bf16 bulk cast ----------
__global__ __launch_bounds__(256) void cast_bf16(const float* __restrict__ x,
                                                 u16* __restrict__ xb, int total4) {
  int i = blockIdx.x * 256 + threadIdx.x;
  if (i < total4) {
    float4 a = ((const float4*)x)[i];
    ushort4 b;
    b.x = f2bf(a.x); b.y = f2bf(a.y); b.z = f2bf(a.z); b.w = f2bf(a.w);
    ((ushort4*)xb)[i] = b;
  }
}

// ---------- no-LDS dual-output MFMA GEMM ----------
__global__ __launch_bounds__(256) void gemm_dual(
    const u16* __restrict__ A, const u16* __restrict__ Wt0,
    const u16* __restrict__ Wt1, u16* __restrict__ C0, u16* __restrict__ C1,
    int N) {
  int w = threadIdx.x >> 6, lane = threadIdx.x & 63;
  int lrow = lane & 15, q = lane >> 4;
  int row0 = blockIdx.x * 128 + w * 32;
  int ra = row0 + lrow;
  int rb = row0 + 16 + lrow;
  f32x4 acc[2][2][8];
#pragma unroll
  for (int o = 0; o < 2; ++o)
#pragma unroll
    for (int i = 0; i < 2; ++i)
#pragma unroll
      for (int j = 0; j < 8; ++j) acc[o][i][j] = (f32x4){0.f, 0.f, 0.f, 0.f};

  const short8 zero8 = {0, 0, 0, 0, 0, 0, 0, 0};
#pragma unroll
  for (int kk = 0; kk < 128; kk += 32) {
    int ko = kk + q * 8;
    short8 a0 = (ra < N) ? *(const short8*)(A + (size_t)ra * 128 + ko) : zero8;
    short8 a1 = (rb < N) ? *(const short8*)(A + (size_t)rb * 128 + ko) : zero8;
#pragma unroll
    for (int j = 0; j < 8; ++j) {
      short8 b0 = *(const short8*)(Wt0 + (j * 16 + lrow) * 128 + ko);
      short8 b1 = *(const short8*)(Wt1 + (j * 16 + lrow) * 128 + ko);
      acc[0][0][j] = __builtin_amdgcn_mfma_f32_16x16x32_bf16(a0, b0, acc[0][0][j], 0, 0, 0);
      acc[0][1][j] = __builtin_amdgcn_mfma_f32_16x16x32_bf16(a1, b0, acc[0][1][j], 0, 0, 0);
      acc[1][0][j] = __builtin_amdgcn_mfma_f32_16x16x32_bf16(a0, b1, acc[1][0][j], 0, 0, 0);
      acc[1][1][j] = __builtin_amdgcn_mfma_f32_16x16x32_bf16(a1, b1, acc[1][1][j], 0, 0, 0);
    }
  }
#pragma unroll
  for (int o = 0; o < 2; ++o) {
    u16* C = o ? C1 : C0;
#pragma unroll
    for (int i = 0; i < 2; ++i) {
#pragma unroll
      for (int r = 0; r < 4; ++r) {
        int grow = row0 + i * 16 + q * 4 + r;
        if (grow < N) {
#pragma unroll
          for (int j = 0; j < 8; ++j) {
            C[(size_t)grow * 128 + j * 16 + lrow] = f2bf(acc[o][i][j][r]);
          }
        }
      }
    }
  }
}

// ---------- ke/ve precompute for BOTH layers in one dispatch ----------
// mat = blockIdx>>1: 0 -> We0 (kep0/vep0), 1 -> We1 (kep1/vep1)
__global__ __launch_bounds__(256) void prep_embs2(
    const float* __restrict__ embA, const float* __restrict__ embB,
    const float* __restrict__ We0, const float* __restrict__ We1,
    float* __restrict__ kv) {  // kv = [kep0|vep0|kep1|vep1], 512 floats each
  int mat = blockIdx.x >> 1;
  int t = (blockIdx.x & 1) * 256 + threadIdx.x;  // 0..511
  const float* We = mat ? We1 : We0;
  float* keOut = kv + mat * 1024;
  float* veOut = keOut + 512;
  int r = t >> 7, c = t & 127;
  float s0 = 0.f, s1 = 0.f;
  for (int k = 0; k < 128; ++k) {
    float w = We[k * 128 + c];
    s0 += embA[r * 128 + k] * w;
    s1 += embB[r * 128 + k] * w;
  }
  keOut[t] = s0;
  veOut[t] = s1;
}

// ---------- CSR build (both layers, rank-based: fill has no atomics) ----------
__global__ __launch_bounds__(256) void csr_count2(
    const int* __restrict__ dst0, const int* __restrict__ dst1,
    int* __restrict__ cnt, int* __restrict__ rank) {
  int t = blockIdx.x * 256 + threadIdx.x;
  if (t < E0N) {
    rank[t] = atomicAdd(&cnt[dst0[t]], 1);
  } else if (t < ET) {
    rank[t] = atomicAdd(&cnt[NE0 + dst1[t - E0N]], 1);
  }
}

__global__ __launch_bounds__(256) void scan1(const int* __restrict__ cnt,
                                             int* __restrict__ excl,
                                             int* __restrict__ blocksums, int N) {
  __shared__ int sh[256];
  int tid = threadIdx.x;
  int base = blockIdx.x * 1024 + tid * 4;
  int v0 = (base + 0 < N) ? cnt[base + 0] : 0;
  int v1 = (base + 1 < N) ? cnt[base + 1] : 0;
  int v2 = (base + 2 < N) ? cnt[base + 2] : 0;
  int v3 = (base + 3 < N) ? cnt[base + 3] : 0;
  int tsum = v0 + v1 + v2 + v3;
  sh[tid] = tsum;
  __syncthreads();
  for (int off = 1; off < 256; off <<= 1) {
    int t2 = (tid >= off) ? sh[tid - off] : 0;
    __syncthreads();
    sh[tid] += t2;
    __syncthreads();
  }
  int incl = sh[tid];
  if (tid == 255) blocksums[blockIdx.x] = incl;
  int run = incl - tsum;
  if (base + 0 < N) excl[base + 0] = run; run += v0;
  if (base + 1 < N) excl[base + 1] = run; run += v1;
  if (base + 2 < N) excl[base + 2] = run; run += v2;
  if (base + 3 < N) excl[base + 3] = run;
}

__global__ void scan2(int* __restrict__ blocksums, int nb) {
  __shared__ int sh[256];
  int tid = threadIdx.x;
  int v = (tid < nb) ? blocksums[tid] : 0;
  sh[tid] = v;
  __syncthreads();
  for (int off = 1; off < 256; off <<= 1) {
    int t2 = (tid >= off) ? sh[tid - off] : 0;
    __syncthreads();
    sh[tid] += t2;
    __syncthreads();
  }
  if (tid < nb) blocksums[tid] = sh[tid] - v;
}

__global__ __launch_bounds__(256) void scan3(int* __restrict__ offs,
                                             const int* __restrict__ blocksums, int N,
                                             int Etot) {
  int t = blockIdx.x * 256 + threadIdx.x;
  if (t < N) offs[t] += blocksums[t >> 10];
  if (t == 0) offs[N] = Etot;
}

__global__ __launch_bounds__(256) void csr_fill2(
    const int* __restrict__ dst0, const int* __restrict__ src0, const int* __restrict__ et0,
    const int* __restrict__ dst1, const int* __restrict__ src1, const int* __restrict__ et1,
    const int* __restrict__ offs, const int* __restrict__ rank,
    int* __restrict__ elist) {
  int t = blockIdx.x * 256 + threadIdx.x;
  if (t < E0N) {
    int p = offs[dst0[t]] + rank[t];
    elist[p] = (src0[t] << 2) | et0[t];
  } else if (t < ET) {
    int t2 = t - E0N;
    int p = offs[NE0 + dst1[t2]] + rank[t];
    elist[p] = (src1[t2] << 2) | et1[t2];
  }
}

// ---------- fused flash attention + skip combine: TWO dsts per wave ----------
// 32 lanes/dst: head = sub>>2, quad = sub&3 -> 4 dims/lane (ushort4 gathers).
// out[d] = 0.5*skip[d] + 0.5 * softmax_e(leaky(q.(k+kt)/4)) . (v+vt)
__device__ __forceinline__ float sel4(float s0, float s1, float s2, float s3, int ty) {
  float a = (ty & 1) ? s1 : s0;
  float b = (ty & 1) ? s3 : s2;
  return (ty & 2) ? b : a;
}

__global__ __launch_bounds__(256) void attn_fused(
    const int* __restrict__ elist, const int* __restrict__ offs,
    const u16* __restrict__ Q, const u16* __restrict__ K,
    const u16* __restrict__ V, const float* __restrict__ ke,
    const float* __restrict__ ve, const u16* __restrict__ skipb,
    float* __restrict__ outp, int N) {
  int wave = (blockIdx.x * 256 + threadIdx.x) >> 6;
  int lane = threadIdx.x & 63;
  int half = lane >> 5;
  int sub = lane & 31;
  int d = wave * 2 + half;
  bool active = d < N;
  int dc = active ? d : 0;
  int dim = (sub >> 2) * 16 + (sub & 3) * 4;  // head*16 + quad*4

  ushort4 qv = *(const ushort4*)(Q + (size_t)dc * D + dim);
  float q0 = bf2f(qv.x) * 0.25f, q1 = bf2f(qv.y) * 0.25f;
  float q2 = bf2f(qv.z) * 0.25f, q3 = bf2f(qv.w) * 0.25f;

  // per-type q.kt (4 scalars after quad reduction)
  float qk[4];
#pragma unroll
  for (int ty = 0; ty < 4; ++ty) {
    float4 kt = *(const float4*)(ke + ty * D + dim);
    float p = q0 * kt.x + q1 * kt.y + q2 * kt.z + q3 * kt.w;
    p += __shfl_xor(p, 1, 64);
    p += __shfl_xor(p, 2, 64);
    qk[ty] = p;
  }

  float m = -INFINITY, s = 0.f;
  float a0d = 0.f, a1d = 0.f, a2d = 0.f, a3d = 0.f;  // 4-dim accumulator
  int j = active ? offs[d] : 0;
  int j1 = active ? offs[d + 1] : 0;

  while (__any(j < j1)) {
    int n = j1 - j;  // may be <= 0 for a finished half
    if (n > 0) {
      int pk0 = elist[j];
      int pk1 = (n > 1) ? elist[j + 1] : pk0;
      int pk2 = (n > 2) ? elist[j + 2] : pk0;
      int pk3 = (n > 3) ? elist[j + 3] : pk0;
      int s0 = pk0 >> 2, t0 = pk0 & 3;
      int s1 = pk1 >> 2, t1 = pk1 & 3;
      int s2 = pk2 >> 2, t2 = pk2 & 3;
      int s3 = pk3 >> 2, t3 = pk3 & 3;
      ushort4 k0 = *(const ushort4*)(K + (size_t)s0 * D + dim);
      ushort4 k1 = *(const ushort4*)(K + (size_t)s1 * D + dim);
      ushort4 k2 = *(const ushort4*)(K + (size_t)s2 * D + dim);
      ushort4 k3 = *(const ushort4*)(K + (size_t)s3 * D + dim);
      ushort4 w0 = *(const ushort4*)(V + (size_t)s0 * D + dim);
      ushort4 w1 = *(const ushort4*)(V + (size_t)s1 * D + dim);
      ushort4 w2 = *(const ushort4*)(V + (size_t)s2 * D + dim);
      ushort4 w3 = *(const ushort4*)(V + (size_t)s3 * D + dim);
      float4 vt0 = *(const float4*)(ve + t0 * D + dim);
      float4 vt1 = *(const float4*)(ve + t1 * D + dim);
      float4 vt2 = *(const float4*)(ve + t2 * D + dim);
      float4 vt3 = *(const float4*)(ve + t3 * D + dim);

      float p0 = q0 * bf2f(k0.x) + q1 * bf2f(k0.y) + q2 * bf2f(k0.z) + q3 * bf2f(k0.w);
      float p1 = q0 * bf2f(k1.x) + q1 * bf2f(k1.y) + q2 * bf2f(k1.z) + q3 * bf2f(k1.w);
      float p2 = q0 * bf2f(k2.x) + q1 * bf2f(k2.y) + q2 * bf2f(k2.z) + q3 * bf2f(k2.w);
      float p3 = q0 * bf2f(k3.x) + q1 * bf2f(k3.y) + q2 * bf2f(k3.z) + q3 * bf2f(k3.w);
      p0 += __shfl_xor(p0, 1, 64); p0 += __shfl_xor(p0, 2, 64);
      p1 += __shfl_xor(p1, 1, 64); p1 += __shfl_xor(p1, 2, 64);
      p2 += __shfl_xor(p2, 1, 64); p2 += __shfl_xor(p2, 2, 64);
      p3 += __shfl_xor(p3, 1, 64); p3 += __shfl_xor(p3, 2, 64);

      float l0 = p0 + sel4(qk[0], qk[1], qk[2], qk[3], t0);
      float l1 = p1 + sel4(qk[0], qk[1], qk[2], qk[3], t1);
      float l2 = p2 + sel4(qk[0], qk[1], qk[2], qk[3], t2);
      float l3 = p3 + sel4(qk[0], qk[1], qk[2], qk[3], t3);
      l0 = l0 >= 0.f ? l0 : 0.2f * l0;
      l1 = l1 >= 0.f ? l1 : 0.2f * l1;
      l2 = l2 >= 0.f ? l2 : 0.2f * l2;
      l3 = l3 >= 0.f ? l3 : 0.2f * l3;
      if (n < 2) l1 = -INFINITY;
      if (n < 3) l2 = -INFINITY;
      if (n < 4) l3 = -INFINITY;
      float mb = fmaxf(fmaxf(l0, l1), fmaxf(l2, l3));  // finite: l0 valid
      float mn = fmaxf(m, mb);
      float f = __expf(m - mn);  // m=-inf, mn finite -> 0
      float a0 = __expf(l0 - mn);
      float a1 = __expf(l1 - mn);
      float a2 = __expf(l2 - mn);
      float a3 = __expf(l3 - mn);
      s = s * f + ((a0 + a1) + (a2 + a3));
      a0d = a0d * f + a0 * (bf2f(w0.x) + vt0.x) + a1 * (bf2f(w1.x) + vt1.x) +
            a2 * (bf2f(w2.x) + vt2.x) + a3 * (bf2f(w3.x) + vt3.x);
      a1d = a1d * f + a0 * (bf2f(w0.y) + vt0.y) + a1 * (bf2f(w1.y) + vt1.y) +
            a2 * (bf2f(w2.y) + vt2.y) + a3 * (bf2f(w3.y) + vt3.y);
      a2d = a2d * f + a0 * (bf2f(w0.z) + vt0.z) + a1 * (bf2f(w1.z) + vt1.z) +
            a2 * (bf2f(w2.z) + vt2.z) + a3 * (bf2f(w3.z) + vt3.z);
      a3d = a3d * f + a0 * (bf2f(w0.w) + vt0.w) + a1 * (bf2f(w1.w) + vt1.w) +
            a2 * (bf2f(w2.w) + vt2.w) + a3 * (bf2f(w3.w) + vt3.w);
      m = mn;
    }
    j += 4;
  }
  if (active) {
    float inv = 1.f / (s + 1e-16f);
    ushort4 sk = *(const ushort4*)(skipb + (size_t)d * D + dim);
    float4 o;
    o.x = 0.5f * bf2f(sk.x) + 0.5f * a0d * inv;
    o.y = 0.5f * bf2f(sk.y) + 0.5f * a1d * inv;
    o.z = 0.5f * bf2f(sk.z) + 0.5f * a2d * inv;
    o.w = 0.5f * bf2f(sk.w) + 0.5f * a3d * inv;
    *(float4*)(outp + (size_t)d * D + dim) = o;
  }
}

// ---------- batch norm ----------
__global__ __launch_bounds__(256) void bn_reduce(const float* __restrict__ h,
                                                 float* __restrict__ sum,
                                                 float* __restrict__ sumsq, int N) {
  int c = threadIdx.x & 127;
  int rofs = threadIdx.x >> 7;
  float s0 = 0.f, s1 = 0.f;
  for (int r = blockIdx.x * 2 + rofs; r < N; r += gridDim.x * 2) {
    float v = h[(size_t)r * 128 + c];
    s0 += v;
    s1 += v * v;
  }
  __shared__ float ls[256], lq[256];
  ls[threadIdx.x] = s0;
  lq[threadIdx.x] = s1;
  __syncthreads();
  if (threadIdx.x < 128) {
    atomicAdd(&sum[c], ls[threadIdx.x] + ls[threadIdx.x + 128]);
    atomicAdd(&sumsq[c], lq[threadIdx.x] + lq[threadIdx.x + 128]);
  }
}

__global__ void bn_finalize(const float* __restrict__ sum, const float* __restrict__ sumsq,
                            const float* __restrict__ gamma, const float* __restrict__ beta,
                            float* __restrict__ scale, float* __restrict__ shift, float invN) {
  int c = threadIdx.x;
  if (c >= 128) return;
  float mu = sum[c] * invN;
  float var = sumsq[c] * invN - mu * mu;
  float inv = rsqrtf(var + 1e-5f);
  float sc = gamma[c] * inv;
  scale[c] = sc;
  shift[c] = beta[c] - mu * sc;
}

__global__ __launch_bounds__(256) void bn_apply(const float* __restrict__ h,
                                                u16* __restrict__ hbf,
                                                const float* __restrict__ scale,
                                                const float* __restrict__ shift, int total) {
  int i = blockIdx.x * 256 + threadIdx.x;
  if (i < total) {
    int c = i & 127;
    hbf[i] = f2bf(h[i] * scale[c] + shift[c]);
  }
}

// ---------- launch ----------
extern "C" void kernel_launch(void* const* d_in, const int* in_sizes, int n_in,
                              void* d_out, int out_size, void* d_ws, size_t ws_size,
                              hipStream_t stream) {
  const float* x        = (const float*)d_in[0];
  const int*   ei0      = (const int*)d_in[1];
  const int*   et0      = (const int*)d_in[2];
  const int*   ei1      = (const int*)d_in[3];
  const int*   et1      = (const int*)d_in[4];
  const float* emb_type = (const float*)d_in[5];
  const float* emb_attr = (const float*)d_in[6];
  const float* v2e_Wq   = (const float*)d_in[7];
  const float* v2e_Wk   = (const float*)d_in[8];
  const float* v2e_Wv   = (const float*)d_in[9];
  const float* v2e_We   = (const float*)d_in[10];
  const float* v2e_Wsk  = (const float*)d_in[11];
  const float* e2_Wq    = (const float*)d_in[12];
  const float* e2_Wk    = (const float*)d_in[13];
  const float* e2_Wv    = (const float*)d_in[14];
  const float* e2_We    = (const float*)d_in[15];
  const float* e2_Wsk   = (const float*)d_in[16];
  const float* bn_gamma = (const float*)d_in[17];
  const float* bn_beta  = (const float*)d_in[18];
  float* out = (float*)d_out;

  // workspace layout (bytes; every chunk 16B-aligned)
  char* wsb = (char*)d_ws;
  size_t off = 0;
  u16* xb  = (u16*)(wsb + off);  off += (size_t)NSRC * D * 2;
  u16* Kb  = (u16*)(wsb + off);  off += (size_t)NSRC * D * 2;
  u16* Vb  = (u16*)(wsb + off);  off += (size_t)NSRC * D * 2;
  u16* Qb  = (u16*)(wsb + off);  off += (size_t)NE0 * D * 2;
  u16* Sb  = (u16*)(wsb + off);  off += (size_t)NE0 * D * 2;
  float* hb = (float*)(wsb + off); off += (size_t)NE0 * D * 4;
  u16* hbf = (u16*)(wsb + off);  off += (size_t)NE0 * D * 2;
  u16* wtAll = (u16*)(wsb + off); off += 8 * 16384 * 2;
  int* elist = (int*)(wsb + off);  off += (size_t)ET * 4;
  int* rank  = (int*)(wsb + off);  off += (size_t)ET * 4;
  int* offs  = (int*)(wsb + off);  off += ((size_t)NT + 8) * 4;
  int* bsums = (int*)(wsb + off);  off += 1024;
  float* kv  = (float*)(wsb + off); off += 4 * 512 * 4;  // kep0|vep0|kep1|vep1
  float* bnsum = (float*)(wsb + off);  off += 512;       // bnsum|bnsq contiguous
  float* bnsq = (float*)(wsb + off);   off += 512;
  float* bnscale = (float*)(wsb + off); off += 512;
  float* bnshift = (float*)(wsb + off); off += 512;

  u16* wtK0 = wtAll + 0 * 16384;
  u16* wtV0 = wtAll + 1 * 16384;
  u16* wtQ0 = wtAll + 2 * 16384;
  u16* wtS0 = wtAll + 3 * 16384;
  u16* wtK1 = wtAll + 4 * 16384;
  u16* wtV1 = wtAll + 5 * 16384;
  u16* wtQ1 = wtAll + 6 * 16384;
  u16* wtS1 = wtAll + 7 * 16384;
  float* kep0 = kv;
  float* vep0 = kv + 512;
  float* kep1 = kv + 1024;
  float* vep1 = kv + 1536;

  const int* src0 = ei0;
  const int* dst0 = ei0 + E0N;
  const int* src1 = ei1;
  const int* dst1 = ei1 + E1N;

  // ===== setup (input-only dependencies) =====
  prep_weights<<<64, 256, 0, stream>>>(v2e_Wk, v2e_Wv, v2e_Wq, v2e_Wsk,
                                       e2_Wk, e2_Wv, e2_Wq, e2_Wsk, wtAll);
  cast_bf16<<<(NSRC * D / 4 + 255) / 256, 256, 0, stream>>>(x, xb, NSRC * D / 4);
  hipMemsetAsync(offs, 0, (size_t)(NT + 1) * 4, stream);
  hipMemsetAsync(bnsum, 0, 256 * 4, stream);  // bnsum + bnsq

  // CSR for both layers, concatenated bins (rank-based fill: no fill atomics)
  csr_count2<<<(ET + 255) / 256, 256, 0, stream>>>(dst0, dst1, offs, rank);
  {
    int nb = (NT + 1023) / 1024;  // 147 <= 256
    scan1<<<nb, 256, 0, stream>>>(offs, offs, bsums, NT);
    scan2<<<1, 256, 0, stream>>>(bsums, nb);
    scan3<<<(NT + 255) / 256, 256, 0, stream>>>(offs, bsums, NT, ET);
  }
  csr_fill2<<<(ET + 255) / 256, 256, 0, stream>>>(dst0, src0, et0, dst1, src1, et1,
                                                  offs, rank, elist);
  prep_embs2<<<4, 256, 0, stream>>>(emb_type, emb_attr, v2e_We, e2_We, kv);

  // ===== layer 0 =====
  gemm_dual<<<(NSRC + 127) / 128, 256, 0, stream>>>(xb, wtK0, wtV0, Kb, Vb, NSRC);
  gemm_dual<<<(NE0 + 127) / 128, 256, 0, stream>>>(xb, wtQ0, wtS0, Qb, Sb, NE0);
  attn_fused<<<(NE0 + 7) / 8, 256, 0, stream>>>(elist, offs, Qb, Kb, Vb, kep0, vep0,
                                                Sb, hb, NE0);
  bn_reduce<<<256, 256, 0, stream>>>(hb, bnsum, bnsq, NE0);
  bn_finalize<<<1, 128, 0, stream>>>(bnsum, bnsq, bn_gamma, bn_beta, bnscale, bnshift,
                                     1.0f / (float)NE0);
  bn_apply<<<(NE0 * D + 255) / 256, 256, 0, stream>>>(hb, hbf, bnscale, bnshift, NE0 * D);

  // ===== layer 1 =====
  gemm_dual<<<(NE0 + 127) / 128, 256, 0, stream>>>(hbf, wtK1, wtV1, Kb, Vb, NE0);
  gemm_dual<<<(NE1 + 127) / 128, 256, 0, stream>>>(hbf, wtQ1, wtS1, Qb, Sb, NE1);
  attn_fused<<<(NE1 + 7) / 8, 256, 0, stream>>>(elist, offs + NE0, Qb, Kb, Vb, kep1, vep1,
                                                Sb, out, NE1);
}

// Round 7
// 742.380 us; speedup vs baseline: 16.1371x; 1.0091x over previous
//
#include <hip/hip_runtime.h>
#include <cstdint>
#include <cstddef>

#define D 128
#define H 8
#define NSRC 200000
#define NE0  100000
#define NE1  50000
#define E0N  1000000
#define E1N  500000
#define NT   (NE0 + NE1)
#define ET   (E0N + E1N)

typedef unsigned short u16;
typedef __attribute__((ext_vector_type(8))) short short8;
typedef __attribute__((ext_vector_type(4))) float f32x4;

// ---------- bf16 helpers ----------
__device__ __forceinline__ u16 f2bf(float f) {
  unsigned u = __float_as_uint(f);
  unsigned r = (u + 0x7fffu + ((u >> 16) & 1u)) >> 16;  // RNE
  return (u16)r;
}
__device__ __forceinline__ float bf2f(u16 u) {
  return __uint_as_float(((unsigned)u) << 16);
}

// ---------- mega-prep: x cast + weight transpose + emb GEMMs + zero-fill ----------
// block roles: [0,BC) cast | [BC,BC+64) weights | +4 embs | +BZ zero offs | +1 zero bn
#define BC 25000            // (NSRC*D/4)/256
#define BZ 147              // ceil((NT+1)/1024) = ceil(150001/1024); WAS 145 -> OOB poison bug (R6)
static_assert((size_t)BZ * 1024 >= NT + 1, "offs zero-fill must cover NT+1 entries");
__global__ __launch_bounds__(256) void prep_all(
    const float* __restrict__ x, u16* __restrict__ xb,
    const float* w0, const float* w1, const float* w2, const float* w3,
    const float* w4, const float* w5, const float* w6, const float* w7,
    u16* __restrict__ wt,
    const float* __restrict__ embA, const float* __restrict__ embB,
    const float* __restrict__ We0, const float* __restrict__ We1,
    float* __restrict__ kv,
    int* __restrict__ offs, float* __restrict__ bnsums) {
  int b = blockIdx.x;
  if (b < BC) {
    int i = b * 256 + threadIdx.x;
    float4 a = ((const float4*)x)[i];
    ushort4 o;
    o.x = f2bf(a.x); o.y = f2bf(a.y); o.z = f2bf(a.z); o.w = f2bf(a.w);
    ((ushort4*)xb)[i] = o;
  } else if (b < BC + 64) {
    int bb = b - BC;
    const float* wsrc[8] = {w0, w1, w2, w3, w4, w5, w6, w7};
    int mat = bb >> 3;
    int blk = bb & 7;
    const float* W = wsrc[mat];
    u16* out = wt + mat * 16384;
    for (int i = blk * 2048 + threadIdx.x; i < (blk + 1) * 2048; i += 256) {
      int n = i >> 7, k = i & 127;
      out[i] = f2bf(W[k * 128 + n]);
    }
  } else if (b < BC + 68) {
    int bb = b - BC - 64;
    int mat = bb >> 1;
    int t = (bb & 1) * 256 + threadIdx.x;
    const float* We = mat ? We1 : We0;
    float* keOut = kv + mat * 1024;
    float* veOut = keOut + 512;
    int r = t >> 7, c = t & 127;
    float s0 = 0.f, s1 = 0.f;
    for (int k = 0; k < 128; ++k) {
      float w = We[k * 128 + c];
      s0 += embA[r * 128 + k] * w;
      s1 += embB[r * 128 + k] * w;
    }
    keOut[t] = s0;
    veOut[t] = s1;
  } else if (b < BC + 68 + BZ) {
    int base = (b - BC - 68) * 1024 + threadIdx.x * 4;
#pragma unroll
    for (int i = 0; i < 4; ++i)
      if (base + i < NT + 1) offs[base + i] = 0;
  } else {
    bnsums[threadIdx.x] = 0.f;  // 256 floats = bnsum|bnsq
  }
}

// ---------- quad-output MFMA GEMM: one dispatch does K/V (rows NA) + Q/S (rows NB)
__global__ __launch_bounds__(256) void gemm_quad(
    const u16* __restrict__ A,
    const u16* __restrict__ WtK, const u16* __restrict__ WtV,
    u16* __restrict__ CK, u16* __restrict__ CV, int NA, int nKV,
    const u16* __restrict__ WtQ, const u16* __restrict__ WtS,
    u16* __restrict__ CQ, u16* __restrict__ CS, int NB) {
  int b = blockIdx.x;
  const u16 *Wt0, *Wt1;
  u16 *C0, *C1;
  int N, row0;
  if (b < nKV) {
    Wt0 = WtK; Wt1 = WtV; C0 = CK; C1 = CV; N = NA; row0 = b * 128;
  } else {
    Wt0 = WtQ; Wt1 = WtS; C0 = CQ; C1 = CS; N = NB; row0 = (b - nKV) * 128;
  }
  int w = threadIdx.x >> 6, lane = threadIdx.x & 63;
  int lrow = lane & 15, q = lane >> 4;
  row0 += w * 32;
  int ra = row0 + lrow;
  int rb = row0 + 16 + lrow;
  f32x4 acc[2][2][8];
#pragma unroll
  for (int o = 0; o < 2; ++o)
#pragma unroll
    for (int i = 0; i < 2; ++i)
#pragma unroll
      for (int j = 0; j < 8; ++j) acc[o][i][j] = (f32x4){0.f, 0.f, 0.f, 0.f};

  const short8 zero8 = {0, 0, 0, 0, 0, 0, 0, 0};
#pragma unroll
  for (int kk = 0; kk < 128; kk += 32) {
    int ko = kk + q * 8;
    short8 a0 = (ra < N) ? *(const short8*)(A + (size_t)ra * 128 + ko) : zero8;
    short8 a1 = (rb < N) ? *(const short8*)(A + (size_t)rb * 128 + ko) : zero8;
#pragma unroll
    for (int j = 0; j < 8; ++j) {
      short8 b0 = *(const short8*)(Wt0 + (j * 16 + lrow) * 128 + ko);
      short8 b1 = *(const short8*)(Wt1 + (j * 16 + lrow) * 128 + ko);
      acc[0][0][j] = __builtin_amdgcn_mfma_f32_16x16x32_bf16(a0, b0, acc[0][0][j], 0, 0, 0);
      acc[0][1][j] = __builtin_amdgcn_mfma_f32_16x16x32_bf16(a1, b0, acc[0][1][j], 0, 0, 0);
      acc[1][0][j] = __builtin_amdgcn_mfma_f32_16x16x32_bf16(a0, b1, acc[1][0][j], 0, 0, 0);
      acc[1][1][j] = __builtin_amdgcn_mfma_f32_16x16x32_bf16(a1, b1, acc[1][1][j], 0, 0, 0);
    }
  }
#pragma unroll
  for (int o = 0; o < 2; ++o) {
    u16* C = o ? C1 : C0;
#pragma unroll
    for (int i = 0; i < 2; ++i) {
#pragma unroll
      for (int r = 0; r < 4; ++r) {
        int grow = row0 + i * 16 + q * 4 + r;
        if (grow < N) {
#pragma unroll
          for (int j = 0; j < 8; ++j) {
            C[(size_t)grow * 128 + j * 16 + lrow] = f2bf(acc[o][i][j][r]);
          }
        }
      }
    }
  }
}

// ---------- CSR build (both layers, rank-based fill) ----------
__global__ __launch_bounds__(256) void csr_count2(
    const int* __restrict__ dst0, const int* __restrict__ dst1,
    int* __restrict__ cnt, int* __restrict__ rank) {
  int t = blockIdx.x * 256 + threadIdx.x;
  if (t < E0N) {
    rank[t] = atomicAdd(&cnt[dst0[t]], 1);
  } else if (t < ET) {
    rank[t] = atomicAdd(&cnt[NE0 + dst1[t - E0N]], 1);
  }
}

__global__ __launch_bounds__(256) void scan1(const int* __restrict__ cnt,
                                             int* __restrict__ excl,
                                             int* __restrict__ blocksums, int N) {
  __shared__ int sh[256];
  int tid = threadIdx.x;
  int base = blockIdx.x * 1024 + tid * 4;
  int v0 = (base + 0 < N) ? cnt[base + 0] : 0;
  int v1 = (base + 1 < N) ? cnt[base + 1] : 0;
  int v2 = (base + 2 < N) ? cnt[base + 2] : 0;
  int v3 = (base + 3 < N) ? cnt[base + 3] : 0;
  int tsum = v0 + v1 + v2 + v3;
  sh[tid] = tsum;
  __syncthreads();
  for (int off = 1; off < 256; off <<= 1) {
    int t2 = (tid >= off) ? sh[tid - off] : 0;
    __syncthreads();
    sh[tid] += t2;
    __syncthreads();
  }
  int incl = sh[tid];
  if (tid == 255) blocksums[blockIdx.x] = incl;
  int run = incl - tsum;
  if (base + 0 < N) excl[base + 0] = run; run += v0;
  if (base + 1 < N) excl[base + 1] = run; run += v1;
  if (base + 2 < N) excl[base + 2] = run; run += v2;
  if (base + 3 < N) excl[base + 3] = run;
}

__global__ void scan2(int* __restrict__ blocksums, int nb) {
  __shared__ int sh[256];
  int tid = threadIdx.x;
  int v = (tid < nb) ? blocksums[tid] : 0;
  sh[tid] = v;
  __syncthreads();
  for (int off = 1; off < 256; off <<= 1) {
    int t2 = (tid >= off) ? sh[tid - off] : 0;
    __syncthreads();
    sh[tid] += t2;
    __syncthreads();
  }
  if (tid < nb) blocksums[tid] = sh[tid] - v;
}

__global__ __launch_bounds__(256) void scan3(int* __restrict__ offs,
                                             const int* __restrict__ blocksums, int N,
                                             int Etot) {
  int t = blockIdx.x * 256 + threadIdx.x;
  if (t < N) offs[t] += blocksums[t >> 10];
  if (t == 0) offs[N] = Etot;
}

__global__ __launch_bounds__(256) void csr_fill2(
    const int* __restrict__ dst0, const int* __restrict__ src0, const int* __restrict__ et0,
    const int* __restrict__ dst1, const int* __restrict__ src1, const int* __restrict__ et1,
    const int* __restrict__ offs, const int* __restrict__ rank,
    int* __restrict__ elist) {
  int t = blockIdx.x * 256 + threadIdx.x;
  if (t < E0N) {
    int p = offs[dst0[t]] + rank[t];
    elist[p] = (src0[t] << 2) | et0[t];
  } else if (t < ET) {
    int t2 = t - E0N;
    int p = offs[NE0 + dst1[t2]] + rank[t];
    elist[p] = (src1[t2] << 2) | et1[t2];
  }
}

// ---------- fused flash attention + skip combine: 2 dsts/wave, 1-batch prefetch ----
__device__ __forceinline__ float sel4(float s0, float s1, float s2, float s3, int ty) {
  float a = (ty & 1) ? s1 : s0;
  float b = (ty & 1) ? s3 : s2;
  return (ty & 2) ? b : a;
}

__global__ __launch_bounds__(256) void attn_fused(
    const int* __restrict__ elist, const int* __restrict__ offs,
    const u16* __restrict__ Q, const u16* __restrict__ K,
    const u16* __restrict__ V, const float* __restrict__ ke,
    const float* __restrict__ ve, const u16* __restrict__ skipb,
    float* __restrict__ outp, int N) {
  int wave = (blockIdx.x * 256 + threadIdx.x) >> 6;
  int lane = threadIdx.x & 63;
  int half = lane >> 5;
  int sub = lane & 31;
  int d = wave * 2 + half;
  bool active = d < N;
  int dc = active ? d : 0;
  int dim = (sub >> 2) * 16 + (sub & 3) * 4;  // head*16 + quad*4

  ushort4 qv = *(const ushort4*)(Q + (size_t)dc * D + dim);
  float q0 = bf2f(qv.x) * 0.25f, q1 = bf2f(qv.y) * 0.25f;
  float q2 = bf2f(qv.z) * 0.25f, q3 = bf2f(qv.w) * 0.25f;

  float qk[4];
#pragma unroll
  for (int ty = 0; ty < 4; ++ty) {
    float4 kt = *(const float4*)(ke + ty * D + dim);
    float p = q0 * kt.x + q1 * kt.y + q2 * kt.z + q3 * kt.w;
    p += __shfl_xor(p, 1, 64);
    p += __shfl_xor(p, 2, 64);
    qk[ty] = p;
  }

  int j0 = active ? offs[d] : 0;
  int j1 = active ? offs[d + 1] : 0;
  int j = j0;

  // prefetched current batch
  int cp0, cp1, cp2, cp3;
  ushort4 ck0, ck1, ck2, ck3, cw0, cw1, cw2, cw3;
  {
    int i0 = (j + 0 < j1) ? j + 0 : 0;
    int i1 = (j + 1 < j1) ? j + 1 : 0;
    int i2 = (j + 2 < j1) ? j + 2 : 0;
    int i3 = (j + 3 < j1) ? j + 3 : 0;
    cp0 = elist[i0]; cp1 = elist[i1]; cp2 = elist[i2]; cp3 = elist[i3];
    ck0 = *(const ushort4*)(K + (size_t)(cp0 >> 2) * D + dim);
    ck1 = *(const ushort4*)(K + (size_t)(cp1 >> 2) * D + dim);
    ck2 = *(const ushort4*)(K + (size_t)(cp2 >> 2) * D + dim);
    ck3 = *(const ushort4*)(K + (size_t)(cp3 >> 2) * D + dim);
    cw0 = *(const ushort4*)(V + (size_t)(cp0 >> 2) * D + dim);
    cw1 = *(const ushort4*)(V + (size_t)(cp1 >> 2) * D + dim);
    cw2 = *(const ushort4*)(V + (size_t)(cp2 >> 2) * D + dim);
    cw3 = *(const ushort4*)(V + (size_t)(cp3 >> 2) * D + dim);
  }

  float m = -INFINITY, s = 0.f;
  float a0d = 0.f, a1d = 0.f, a2d = 0.f, a3d = 0.f;

  while (__any(j < j1)) {
    int jn = j + 4;
    // issue next batch's loads (clamped; consumed next iteration)
    int i0 = (jn + 0 < j1) ? jn + 0 : 0;
    int i1 = (jn + 1 < j1) ? jn + 1 : 0;
    int i2 = (jn + 2 < j1) ? jn + 2 : 0;
    int i3 = (jn + 3 < j1) ? jn + 3 : 0;
    int np0 = elist[i0], np1 = elist[i1], np2 = elist[i2], np3 = elist[i3];
    ushort4 nk0 = *(const ushort4*)(K + (size_t)(np0 >> 2) * D + dim);
    ushort4 nk1 = *(const ushort4*)(K + (size_t)(np1 >> 2) * D + dim);
    ushort4 nk2 = *(const ushort4*)(K + (size_t)(np2 >> 2) * D + dim);
    ushort4 nk3 = *(const ushort4*)(K + (size_t)(np3 >> 2) * D + dim);
    ushort4 nw0 = *(const ushort4*)(V + (size_t)(np0 >> 2) * D + dim);
    ushort4 nw1 = *(const ushort4*)(V + (size_t)(np1 >> 2) * D + dim);
    ushort4 nw2 = *(const ushort4*)(V + (size_t)(np2 >> 2) * D + dim);
    ushort4 nw3 = *(const ushort4*)(V + (size_t)(np3 >> 2) * D + dim);

    int n = j1 - j;
    if (n > 0) {
      int t0 = cp0 & 3, t1 = cp1 & 3, t2 = cp2 & 3, t3 = cp3 & 3;
      float4 vt0 = *(const float4*)(ve + t0 * D + dim);
      float4 vt1 = *(const float4*)(ve + t1 * D + dim);
      float4 vt2 = *(const float4*)(ve + t2 * D + dim);
      float4 vt3 = *(const float4*)(ve + t3 * D + dim);

      float p0 = q0 * bf2f(ck0.x) + q1 * bf2f(ck0.y) + q2 * bf2f(ck0.z) + q3 * bf2f(ck0.w);
      float p1 = q0 * bf2f(ck1.x) + q1 * bf2f(ck1.y) + q2 * bf2f(ck1.z) + q3 * bf2f(ck1.w);
      float p2 = q0 * bf2f(ck2.x) + q1 * bf2f(ck2.y) + q2 * bf2f(ck2.z) + q3 * bf2f(ck2.w);
      float p3 = q0 * bf2f(ck3.x) + q1 * bf2f(ck3.y) + q2 * bf2f(ck3.z) + q3 * bf2f(ck3.w);
      p0 += __shfl_xor(p0, 1, 64); p0 += __shfl_xor(p0, 2, 64);
      p1 += __shfl_xor(p1, 1, 64); p1 += __shfl_xor(p1, 2, 64);
      p2 += __shfl_xor(p2, 1, 64); p2 += __shfl_xor(p2, 2, 64);
      p3 += __shfl_xor(p3, 1, 64); p3 += __shfl_xor(p3, 2, 64);

      float l0 = p0 + sel4(qk[0], qk[1], qk[2], qk[3], t0);
      float l1 = p1 + sel4(qk[0], qk[1], qk[2], qk[3], t1);
      float l2 = p2 + sel4(qk[0], qk[1], qk[2], qk[3], t2);
      float l3 = p3 + sel4(qk[0], qk[1], qk[2], qk[3], t3);
      l0 = l0 >= 0.f ? l0 : 0.2f * l0;
      l1 = l1 >= 0.f ? l1 : 0.2f * l1;
      l2 = l2 >= 0.f ? l2 : 0.2f * l2;
      l3 = l3 >= 0.f ? l3 : 0.2f * l3;
      if (n < 2) l1 = -INFINITY;
      if (n < 3) l2 = -INFINITY;
      if (n < 4) l3 = -INFINITY;
      float mb = fmaxf(fmaxf(l0, l1), fmaxf(l2, l3));
      float mn = fmaxf(m, mb);
      float f = __expf(m - mn);
      float a0 = __expf(l0 - mn);
      float a1 = __expf(l1 - mn);
      float a2 = __expf(l2 - mn);
      float a3 = __expf(l3 - mn);
      s = s * f + ((a0 + a1) + (a2 + a3));
      a0d = a0d * f + a0 * (bf2f(cw0.x) + vt0.x) + a1 * (bf2f(cw1.x) + vt1.x) +
            a2 * (bf2f(cw2.x) + vt2.x) + a3 * (bf2f(cw3.x) + vt3.x);
      a1d = a1d * f + a0 * (bf2f(cw0.y) + vt0.y) + a1 * (bf2f(cw1.y) + vt1.y) +
            a2 * (bf2f(cw2.y) + vt2.y) + a3 * (bf2f(cw3.y) + vt3.y);
      a2d = a2d * f + a0 * (bf2f(cw0.z) + vt0.z) + a1 * (bf2f(cw1.z) + vt1.z) +
            a2 * (bf2f(cw2.z) + vt2.z) + a3 * (bf2f(cw3.z) + vt3.z);
      a3d = a3d * f + a0 * (bf2f(cw0.w) + vt0.w) + a1 * (bf2f(cw1.w) + vt1.w) +
            a2 * (bf2f(cw2.w) + vt2.w) + a3 * (bf2f(cw3.w) + vt3.w);
      m = mn;
    }
    cp0 = np0; cp1 = np1; cp2 = np2; cp3 = np3;
    ck0 = nk0; ck1 = nk1; ck2 = nk2; ck3 = nk3;
    cw0 = nw0; cw1 = nw1; cw2 = nw2; cw3 = nw3;
    j = jn;
  }
  if (active) {
    float inv = 1.f / (s + 1e-16f);
    ushort4 sk = *(const ushort4*)(skipb + (size_t)d * D + dim);
    float4 o;
    o.x = 0.5f * bf2f(sk.x) + 0.5f * a0d * inv;
    o.y = 0.5f * bf2f(sk.y) + 0.5f * a1d * inv;
    o.z = 0.5f * bf2f(sk.z) + 0.5f * a2d * inv;
    o.w = 0.5f * bf2f(sk.w) + 0.5f * a3d * inv;
    *(float4*)(outp + (size_t)d * D + dim) = o;
  }
}

// ---------- batch norm ----------
__global__ __launch_bounds__(256) void bn_reduce(const float* __restrict__ h,
                                                 float* __restrict__ sums, int N) {
  int c = threadIdx.x & 127;
  int rofs = threadIdx.x >> 7;
  float s0 = 0.f, s1 = 0.f;
  for (int r = blockIdx.x * 2 + rofs; r < N; r += gridDim.x * 2) {
    float v = h[(size_t)r * 128 + c];
    s0 += v;
    s1 += v * v;
  }
  __shared__ float ls[256], lq[256];
  ls[threadIdx.x] = s0;
  lq[threadIdx.x] = s1;
  __syncthreads();
  if (threadIdx.x < 128) {
    atomicAdd(&sums[c], ls[threadIdx.x] + ls[threadIdx.x + 128]);
    atomicAdd(&sums[128 + c], lq[threadIdx.x] + lq[threadIdx.x + 128]);
  }
}

// finalize folded in: each block derives scale/shift from sums
__global__ __launch_bounds__(256) void bn_apply(const float* __restrict__ h,
                                                u16* __restrict__ hbf,
                                                const float* __restrict__ sums,
                                                const float* __restrict__ gamma,
                                                const float* __restrict__ beta,
                                                float invN, int total) {
  __shared__ float sc[128], sh[128];
  int tid = threadIdx.x;
  if (tid < 128) {
    float mu = sums[tid] * invN;
    float var = sums[128 + tid] * invN - mu * mu;
    float inv = rsqrtf(var + 1e-5f);
    float s = gamma[tid] * inv;
    sc[tid] = s;
    sh[tid] = beta[tid] - mu * s;
  }
  __syncthreads();
  int i = blockIdx.x * 256 + tid;
  if (i < total) {
    int c = i & 127;
    hbf[i] = f2bf(h[i] * sc[c] + sh[c]);
  }
}

// ---------- launch ----------
extern "C" void kernel_launch(void* const* d_in, const int* in_sizes, int n_in,
                              void* d_out, int out_size, void* d_ws, size_t ws_size,
                              hipStream_t stream) {
  const float* x        = (const float*)d_in[0];
  const int*   ei0      = (const int*)d_in[1];
  const int*   et0      = (const int*)d_in[2];
  const int*   ei1      = (const int*)d_in[3];
  const int*   et1      = (const int*)d_in[4];
  const float* emb_type = (const float*)d_in[5];
  const float* emb_attr = (const float*)d_in[6];
  const float* v2e_Wq   = (const float*)d_in[7];
  const float* v2e_Wk   = (const float*)d_in[8];
  const float* v2e_Wv   = (const float*)d_in[9];
  const float* v2e_We   = (const float*)d_in[10];
  const float* v2e_Wsk  = (const float*)d_in[11];
  const float* e2_Wq    = (const float*)d_in[12];
  const float* e2_Wk    = (const float*)d_in[13];
  const float* e2_Wv    = (const float*)d_in[14];
  const float* e2_We    = (const float*)d_in[15];
  const float* e2_Wsk   = (const float*)d_in[16];
  const float* bn_gamma = (const float*)d_in[17];
  const float* bn_beta  = (const float*)d_in[18];
  float* out = (float*)d_out;

  // workspace layout
  char* wsb = (char*)d_ws;
  size_t off = 0;
  u16* xb  = (u16*)(wsb + off);  off += (size_t)NSRC * D * 2;
  u16* Kb  = (u16*)(wsb + off);  off += (size_t)NSRC * D * 2;
  u16* Vb  = (u16*)(wsb + off);  off += (size_t)NSRC * D * 2;
  u16* Qb  = (u16*)(wsb + off);  off += (size_t)NE0 * D * 2;
  u16* Sb  = (u16*)(wsb + off);  off += (size_t)NE0 * D * 2;
  float* hb = (float*)(wsb + off); off += (size_t)NE0 * D * 4;
  u16* hbf = (u16*)(wsb + off);  off += (size_t)NE0 * D * 2;
  u16* wtAll = (u16*)(wsb + off); off += 8 * 16384 * 2;
  int* elist = (int*)(wsb + off);  off += (size_t)ET * 4;
  int* rank  = (int*)(wsb + off);  off += (size_t)ET * 4;
  int* offs  = (int*)(wsb + off);  off += ((size_t)NT + 8) * 4;
  int* bsums = (int*)(wsb + off);  off += 1024;
  float* kv  = (float*)(wsb + off); off += 4 * 512 * 4;
  float* bnsums = (float*)(wsb + off); off += 256 * 4;  // sum[128] | sumsq[128]

  u16* wtK0 = wtAll + 0 * 16384;
  u16* wtV0 = wtAll + 1 * 16384;
  u16* wtQ0 = wtAll + 2 * 16384;
  u16* wtS0 = wtAll + 3 * 16384;
  u16* wtK1 = wtAll + 4 * 16384;
  u16* wtV1 = wtAll + 5 * 16384;
  u16* wtQ1 = wtAll + 6 * 16384;
  u16* wtS1 = wtAll + 7 * 16384;
  float* kep0 = kv;
  float* vep0 = kv + 512;
  float* kep1 = kv + 1024;
  float* vep1 = kv + 1536;

  const int* src0 = ei0;
  const int* dst0 = ei0 + E0N;
  const int* src1 = ei1;
  const int* dst1 = ei1 + E1N;

  // 1: mega-prep (cast + weights + embs + zeroing)
  prep_all<<<BC + 64 + 4 + BZ + 1, 256, 0, stream>>>(
      x, xb, v2e_Wk, v2e_Wv, v2e_Wq, v2e_Wsk, e2_Wk, e2_Wv, e2_Wq, e2_Wsk,
      wtAll, emb_type, emb_attr, v2e_We, e2_We, kv, offs, bnsums);

  // 2-6: CSR for both layers
  csr_count2<<<(ET + 255) / 256, 256, 0, stream>>>(dst0, dst1, offs, rank);
  {
    int nb = (NT + 1023) / 1024;
    scan1<<<nb, 256, 0, stream>>>(offs, offs, bsums, NT);
    scan2<<<1, 256, 0, stream>>>(bsums, nb);
    scan3<<<(NT + 255) / 256, 256, 0, stream>>>(offs, bsums, NT, ET);
  }
  csr_fill2<<<(ET + 255) / 256, 256, 0, stream>>>(dst0, src0, et0, dst1, src1, et1,
                                                  offs, rank, elist);

  // 7-10: layer 0
  {
    int nKV = (NSRC + 127) / 128, nQS = (NE0 + 127) / 128;
    gemm_quad<<<nKV + nQS, 256, 0, stream>>>(xb, wtK0, wtV0, Kb, Vb, NSRC, nKV,
                                             wtQ0, wtS0, Qb, Sb, NE0);
  }
  attn_fused<<<(NE0 + 7) / 8, 256, 0, stream>>>(elist, offs, Qb, Kb, Vb, kep0, vep0,
                                                Sb, hb, NE0);
  bn_reduce<<<256, 256, 0, stream>>>(hb, bnsums, NE0);
  bn_apply<<<(NE0 * D + 255) / 256, 256, 0, stream>>>(hb, hbf, bnsums, bn_gamma, bn_beta,
                                                      1.0f / (float)NE0, NE0 * D);

  // 11-12: layer 1
  {
    int nKV = (NE0 + 127) / 128, nQS = (NE1 + 127) / 128;
    gemm_quad<<<nKV + nQS, 256, 0, stream>>>(hbf, wtK1, wtV1, Kb, Vb, NE0, nKV,
                                             wtQ1, wtS1, Qb, Sb, NE1);
  }
  attn_fused<<<(NE1 + 7) / 8, 256, 0, stream>>>(elist, offs + NE0, Qb, Kb, Vb, kep1, vep1,
                                                Sb, out, NE1);
}